// Round 10
// baseline (335.880 us; speedup 1.0000x reference)
//
#include <hip/hip_runtime.h>
#include <hip/hip_bf16.h>
#include <math.h>

#define BB 2
#define TT 2048
#define EE 2048
#define HH 16
#define DD 128
#define CC 2048
#define KCONV 4
#define CHUNK 128
#define NC 16          // TT / CHUNK
#define GN_EPS 1e-5f

typedef __bf16 bf16x8 __attribute__((ext_vector_type(8)));
typedef __bf16 bf16x4 __attribute__((ext_vector_type(4)));
typedef float  f32x4  __attribute__((ext_vector_type(4)));

#define GLD16(gp, lp)                                                          \
  __builtin_amdgcn_global_load_lds(                                            \
      (const __attribute__((address_space(1))) void*)(gp),                     \
      (__attribute__((address_space(3))) void*)(lp), 16, 0, 0)

// swizzled fragment load: row-major [128][128] bf16 tile, 16B-group XOR swizzle
__device__ __forceinline__ bf16x8 ldfrag(const __bf16* buf, int row, int kg)
{
  return *(const bf16x8*)(buf + row * 128 + ((kg ^ (row & 7)) << 3));
}

// ---------------------------------------------------------------------------
// merged f32 -> bf16 conversion for x, Wq|Wk|Wv|Wgate (into Wcat), Wo.
// ---------------------------------------------------------------------------
__global__ __launch_bounds__(256)
void convert_all(const float* __restrict__ x,  const float* __restrict__ Wq,
                 const float* __restrict__ Wk, const float* __restrict__ Wv,
                 const float* __restrict__ Wg, const float* __restrict__ Wo,
                 __bf16* __restrict__ xbf, __bf16* __restrict__ Wcat,
                 __bf16* __restrict__ Wob)
{
  const int i = (blockIdx.x * 256 + threadIdx.x) * 4;
  const int XN = 8388608, WN = 4194304;
  const float* src;
  __bf16* dst;
  int off;
  if (i < XN) { src = x; dst = xbf; off = i; }
  else if (i < XN + 4 * WN) {
    const int j = i - XN;
    const int seg = j >> 22;
    src = seg == 0 ? Wq : seg == 1 ? Wk : seg == 2 ? Wv : Wg;
    dst = Wcat + ((size_t)seg << 22);
    off = j & (WN - 1);
  } else { src = Wo; dst = Wob; off = i - XN - 4 * WN; }
  const float4 v = *(const float4*)(src + off);
  bf16x4 o;
  o[0] = (__bf16)v.x; o[1] = (__bf16)v.y; o[2] = (__bf16)v.z; o[3] = (__bf16)v.w;
  *(bf16x4*)(dst + off) = o;
}

// ---------------------------------------------------------------------------
// beta = sigmoid(x @ Wbeta^T), x fp32 (B*T, E), Wbeta (16, E).
// ---------------------------------------------------------------------------
__global__ __launch_bounds__(256)
void beta_ker(const float* __restrict__ x, const float* __restrict__ Wb,
              float* __restrict__ betab)
{
  __shared__ float wsb[16 * 1024];   // 64 KB
  const int tid = threadIdx.x;
  const int w = tid >> 6, lane = tid & 63;
  const int row = blockIdx.x * 4 + w;           // < B*T = 4096
  const float* xrow = x + (size_t)row * EE;

  float acc[16] = {};
#pragma unroll
  for (int kt = 0; kt < 2; ++kt) {
    __syncthreads();
#pragma unroll
    for (int it = 0; it < 16; ++it) {
      const int i = tid + it * 256;
      const int h = i >> 8, kq = i & 255;
      *(float4*)&wsb[h * 1024 + kq * 4] =
          *(const float4*)(Wb + (size_t)h * EE + kt * 1024 + kq * 4);
    }
    __syncthreads();
#pragma unroll
    for (int j = 0; j < 4; ++j) {
      const int kof = lane * 4 + j * 256;
      const float4 xv = *(const float4*)(xrow + kt * 1024 + kof);
#pragma unroll
      for (int h = 0; h < 16; ++h) {
        const float4 wv = *(const float4*)&wsb[h * 1024 + kof];
        acc[h] += xv.x * wv.x + xv.y * wv.y + xv.z * wv.z + xv.w * wv.w;
      }
    }
  }
#pragma unroll
  for (int h = 0; h < 16; ++h) {
#pragma unroll
    for (int off = 32; off; off >>= 1)
      acc[h] += __shfl_xor(acc[h], off, 64);
  }
#pragma unroll
  for (int h = 0; h < 16; ++h)
    if (lane == h)
      betab[(size_t)row * HH + h] = 1.f / (1.f + expf(-acc[h]));
}

// ---------------------------------------------------------------------------
// 256x256 deep-pipelined bf16 GEMM (QKV+gate merged), K=2048, BK=64.
// 8 waves (2Mx4N). LDS = 3 A-bufs + 2 B-bufs = 160 KiB.
// m201 8-phase template: per phase {ds_reads -> stage 1 half -> [lgkmcnt(8)]
// -> barrier -> lgkmcnt(0)+sched_barrier -> setprio(1) -> 16 MFMA ->
// setprio(0) -> barrier}. Stage slots: q0:B(t+1,1) q1:A(t+2,0) q2:A(t+2,1)
// q3:B(t+2,0)+vmcnt(6). Ledger: vmcnt(6) at t.q3 retires ALL of tile t+1.
// ---------------------------------------------------------------------------
__global__ __launch_bounds__(512)
void gemm_big(const __bf16* __restrict__ A, const __bf16* __restrict__ Bm,
              __bf16* __restrict__ o0, __bf16* __restrict__ o1,
              __bf16* __restrict__ o2, __bf16* __restrict__ o3)
{
  __shared__ __attribute__((aligned(16))) unsigned char smem[163840];
  __bf16 (*ldsA)[256 * 64] = (__bf16(*)[256 * 64])smem;             // 3 x 32KB
  __bf16 (*ldsB)[256 * 64] = (__bf16(*)[256 * 64])(smem + 98304);   // 2 x 32KB

  const int tid = threadIdx.x;
  const int w = tid >> 6, l = tid & 63;
  const int wm = w >> 2, wn = w & 3;          // 2 x 4 wave grid
  const int m0 = blockIdx.y * 256, n0 = blockIdx.x * 256;
  const int NT = EE / 64;                     // 32 K-tiles

  const int sr0 = w * 8 + (l >> 3);           // staging dest row, 0..63
  const int skg = l & 7;                      // dest 16B chunk in 128B row
  const int fr = l & 15;
  const int fkg = l >> 4;                     // 0..3

#define STAGE_A(tile, half) do {                                               \
    const int b_ = (tile) % 3;                                                 \
    const int r0_ = sr0;                                                       \
    const int r1_ = 64 + sr0;                                                  \
    GLD16(A + (size_t)(m0 + (half) * 128 + r0_) * 2048 + (tile) * 64           \
              + ((skg ^ (r0_ & 7)) << 3),                                      \
          ldsA[b_] + ((half) * 128 + w * 8) * 64);                             \
    GLD16(A + (size_t)(m0 + (half) * 128 + r1_) * 2048 + (tile) * 64           \
              + ((skg ^ (r1_ & 7)) << 3),                                      \
          ldsA[b_] + ((half) * 128 + 64 + w * 8) * 64);                        \
  } while (0)

#define STAGE_B(tile, half) do {                                               \
    const int b_ = (tile) & 1;                                                 \
    const int r0_ = sr0;                                                       \
    const int r1_ = 64 + sr0;                                                  \
    GLD16(Bm + (size_t)(n0 + (half) * 128 + r0_) * 2048 + (tile) * 64          \
              + ((skg ^ (r0_ & 7)) << 3),                                      \
          ldsB[b_] + ((half) * 128 + w * 8) * 64);                             \
    GLD16(Bm + (size_t)(n0 + (half) * 128 + r1_) * 2048 + (tile) * 64          \
              + ((skg ^ (r1_ & 7)) << 3),                                      \
          ldsB[b_] + ((half) * 128 + 64 + w * 8) * 64);                        \
  } while (0)

#define LDA_FRAG(dst, ab, q, mf, ks) do {                                      \
    const int row_ = wm * 128 + (q) * 32 + (mf) * 16 + fr;                     \
    const int kg_ = (ks) * 4 + fkg;                                            \
    dst = *(const bf16x8*)&ldsA[ab][row_ * 64 + ((kg_ ^ (row_ & 7)) << 3)];    \
  } while (0)
#define LDB_FRAG(dst, bb, nf, ks) do {                                         \
    const int row_ = wn * 64 + (nf) * 16 + fr;                                 \
    const int kg_ = (ks) * 4 + fkg;                                            \
    dst = *(const bf16x8*)&ldsB[bb][row_ * 64 + ((kg_ ^ (row_ & 7)) << 3)];    \
  } while (0)

// 16-MFMA cluster for quadrant q (acc rows 2q, 2q+1)
#define MFMA16(Q) do {                                                         \
    __builtin_amdgcn_s_setprio(1);                                             \
    _Pragma("unroll")                                                          \
    for (int mf = 0; mf < 2; ++mf)                                             \
      _Pragma("unroll")                                                        \
      for (int nf = 0; nf < 4; ++nf)                                           \
        _Pragma("unroll")                                                      \
        for (int ks = 0; ks < 2; ++ks)                                         \
          acc[2 * (Q) + mf][nf] = __builtin_amdgcn_mfma_f32_16x16x32_bf16(     \
              af[mf][ks], bfr[nf][ks], acc[2 * (Q) + mf][nf], 0, 0, 0);        \
    __builtin_amdgcn_s_setprio(0);                                             \
  } while (0)

  f32x4 acc[8][4] = {};

  // prologue: 14 loads; vmcnt(6) -> tile 0 fully resident.
  STAGE_A(0, 0); STAGE_A(0, 1); STAGE_B(0, 0); STAGE_B(0, 1);
  STAGE_A(1, 0); STAGE_A(1, 1); STAGE_B(1, 0);
  asm volatile("s_waitcnt vmcnt(6)" ::: "memory");
  __builtin_amdgcn_s_barrier();

  for (int t = 0; t < NT; ++t) {
    const int abuf = t % 3;
    const int bbuf = t & 1;
    bf16x8 bfr[4][2];

    // ---- phase q0: 8 B-frags + 4 A-frags; stage B(t+1,1)
    {
      bf16x8 af[2][2];
#pragma unroll
      for (int nf = 0; nf < 4; ++nf)
#pragma unroll
        for (int ks = 0; ks < 2; ++ks) LDB_FRAG(bfr[nf][ks], bbuf, nf, ks);
#pragma unroll
      for (int mf = 0; mf < 2; ++mf)
#pragma unroll
        for (int ks = 0; ks < 2; ++ks) LDA_FRAG(af[mf][ks], abuf, 0, mf, ks);
      if (t + 1 < NT) STAGE_B(t + 1, 1);
      asm volatile("s_waitcnt lgkmcnt(8)" ::: "memory");
      __builtin_amdgcn_s_barrier();
      asm volatile("s_waitcnt lgkmcnt(0)" ::: "memory");
      __builtin_amdgcn_sched_barrier(0);
      MFMA16(0);
      __builtin_amdgcn_s_barrier();
    }

    // ---- phase q1: 4 A-frags; stage A(t+2,0)
    {
      bf16x8 af[2][2];
#pragma unroll
      for (int mf = 0; mf < 2; ++mf)
#pragma unroll
        for (int ks = 0; ks < 2; ++ks) LDA_FRAG(af[mf][ks], abuf, 1, mf, ks);
      if (t + 2 < NT) STAGE_A(t + 2, 0);
      __builtin_amdgcn_s_barrier();
      asm volatile("s_waitcnt lgkmcnt(0)" ::: "memory");
      __builtin_amdgcn_sched_barrier(0);
      MFMA16(1);
      __builtin_amdgcn_s_barrier();
    }

    // ---- phase q2: 4 A-frags; stage A(t+2,1)
    {
      bf16x8 af[2][2];
#pragma unroll
      for (int mf = 0; mf < 2; ++mf)
#pragma unroll
        for (int ks = 0; ks < 2; ++ks) LDA_FRAG(af[mf][ks], abuf, 2, mf, ks);
      if (t + 2 < NT) STAGE_A(t + 2, 1);
      __builtin_amdgcn_s_barrier();
      asm volatile("s_waitcnt lgkmcnt(0)" ::: "memory");
      __builtin_amdgcn_sched_barrier(0);
      MFMA16(2);
      __builtin_amdgcn_s_barrier();
    }

    // ---- phase q3: 4 A-frags; stage B(t+2,0); vmcnt(6) once per K-tile
    {
      bf16x8 af[2][2];
#pragma unroll
      for (int mf = 0; mf < 2; ++mf)
#pragma unroll
        for (int ks = 0; ks < 2; ++ks) LDA_FRAG(af[mf][ks], abuf, 3, mf, ks);
      if (t + 2 < NT) STAGE_B(t + 2, 0);
      if (t == NT - 2)     asm volatile("s_waitcnt vmcnt(0)" ::: "memory");
      else if (t < NT - 2) asm volatile("s_waitcnt vmcnt(6)" ::: "memory");
      __builtin_amdgcn_s_barrier();
      asm volatile("s_waitcnt lgkmcnt(0)" ::: "memory");
      __builtin_amdgcn_sched_barrier(0);
      MFMA16(3);
      __builtin_amdgcn_s_barrier();
    }
  }

  // epilogue through LDS: per-wave 128x72 padded tile, coalesced bf16x8 stores
  __syncthreads();
  const int proj = n0 >> 11;
  const int nb = n0 & 2047;
  __bf16* outp = proj == 0 ? o0 : proj == 1 ? o1 : proj == 2 ? o2 : o3;
  __bf16* ep = (__bf16*)smem + (size_t)w * 9216;
  const int crow = (l >> 4) * 4;
#pragma unroll
  for (int mf2 = 0; mf2 < 8; ++mf2)
#pragma unroll
    for (int nf = 0; nf < 4; ++nf)
#pragma unroll
      for (int r = 0; r < 4; ++r) {
        const int row = mf2 * 16 + crow + r;
        float vv = acc[mf2][nf][r];
        if (proj == 3) vv = 1.f / (1.f + expf(-vv));
        ep[row * 72 + nf * 16 + fr] = (__bf16)vv;
      }
#pragma unroll
  for (int it = 0; it < 16; ++it) {
    const int row = it * 8 + (l >> 3);
    const int c8 = (l & 7) * 8;
    const bf16x8 v8 = *(const bf16x8*)&ep[row * 72 + c8];
    *(bf16x8*)(outp + (size_t)(m0 + wm * 128 + row) * 2048 + nb + wn * 64 + c8) = v8;
  }
#undef STAGE_A
#undef STAGE_B
#undef LDA_FRAG
#undef LDB_FRAG
#undef MFMA16
}

// ---------------------------------------------------------------------------
// Wo GEMM, pipelined: BM=128 x BN=256, grid (8,32)=256 blocks (1/CU).
// 8 waves (2Mx4N), per-wave C = 64x64. LDS: 3 A-bufs(16K) + 3 B-bufs(32K)=144K.
// ONE phase per K-tile: vmcnt -> barrier -> reads -> stages(t+2) -> 32 MFMA.
// ---------------------------------------------------------------------------
__global__ __launch_bounds__(512)
void gemm_wo(const __bf16* __restrict__ A, const __bf16* __restrict__ Bm,
             float* __restrict__ Cm)
{
  __shared__ __attribute__((aligned(16))) unsigned char smem[147456];
  __bf16 (*ldsA)[128 * 64] = (__bf16(*)[128 * 64])smem;              // 3 x 16KB
  __bf16 (*ldsB)[256 * 64] = (__bf16(*)[256 * 64])(smem + 49152);    // 3 x 32KB

  const int tid = threadIdx.x;
  const int w = tid >> 6, l = tid & 63;
  const int wm = w >> 2, wn = w & 3;
  const int m0 = blockIdx.y * 128, n0 = blockIdx.x * 256;
  const int NT = CC / 64;                     // 32 K-tiles

  const int sr0 = w * 8 + (l >> 3);
  const int skg = l & 7;
  const int fr = l & 15;
  const int fkg = l >> 4;

#define STAGE_AW(tile) do {                                                    \
    const int b_ = (tile) % 3;                                                 \
    const int r0_ = sr0;                                                       \
    const int r1_ = 64 + sr0;                                                  \
    GLD16(A + (size_t)(m0 + r0_) * 2048 + (tile) * 64                          \
              + ((skg ^ (r0_ & 7)) << 3),                                      \
          ldsA[b_] + (w * 8) * 64);                                            \
    GLD16(A + (size_t)(m0 + r1_) * 2048 + (tile) * 64                          \
              + ((skg ^ (r1_ & 7)) << 3),                                      \
          ldsA[b_] + (64 + w * 8) * 64);                                       \
  } while (0)

#define STAGE_BW(tile, half) do {                                              \
    const int b_ = (tile) % 3;                                                 \
    const int r0_ = sr0;                                                       \
    const int r1_ = 64 + sr0;                                                  \
    GLD16(Bm + (size_t)(n0 + (half) * 128 + r0_) * 2048 + (tile) * 64          \
              + ((skg ^ (r0_ & 7)) << 3),                                      \
          ldsB[b_] + ((half) * 128 + w * 8) * 64);                             \
    GLD16(Bm + (size_t)(n0 + (half) * 128 + r1_) * 2048 + (tile) * 64          \
              + ((skg ^ (r1_ & 7)) << 3),                                      \
          ldsB[b_] + ((half) * 128 + 64 + w * 8) * 64);                        \
  } while (0)

#define LDA_FRAGW(dst, ab, mf, ks) do {                                        \
    const int row_ = wm * 64 + (mf) * 16 + fr;                                 \
    const int kg_ = (ks) * 4 + fkg;                                            \
    dst = *(const bf16x8*)&ldsA[ab][row_ * 64 + ((kg_ ^ (row_ & 7)) << 3)];    \
  } while (0)
#define LDB_FRAGW(dst, bb, nf, ks) do {                                        \
    const int row_ = wn * 64 + (nf) * 16 + fr;                                 \
    const int kg_ = (ks) * 4 + fkg;                                            \
    dst = *(const bf16x8*)&ldsB[bb][row_ * 64 + ((kg_ ^ (row_ & 7)) << 3)];    \
  } while (0)

  f32x4 acc[4][4] = {};

  // prologue: tiles 0 and 1 staged (12 loads).
  STAGE_BW(0, 0); STAGE_BW(0, 1); STAGE_AW(0);
  STAGE_BW(1, 0); STAGE_BW(1, 1); STAGE_AW(1);

  for (int t = 0; t < NT; ++t) {
    const int buf = t % 3;
    bf16x8 bfr[4][2];
    bf16x8 af[4][2];

    if (t == NT - 1) asm volatile("s_waitcnt vmcnt(0)" ::: "memory");
    else             asm volatile("s_waitcnt vmcnt(6)" ::: "memory");
    __builtin_amdgcn_s_barrier();

#pragma unroll
    for (int nf = 0; nf < 4; ++nf)
#pragma unroll
      for (int ks = 0; ks < 2; ++ks) LDB_FRAGW(bfr[nf][ks], buf, nf, ks);
#pragma unroll
    for (int mf = 0; mf < 4; ++mf)
#pragma unroll
      for (int ks = 0; ks < 2; ++ks) LDA_FRAGW(af[mf][ks], buf, mf, ks);

    if (t + 2 < NT) { STAGE_BW(t + 2, 0); STAGE_BW(t + 2, 1); STAGE_AW(t + 2); }

    __builtin_amdgcn_s_setprio(1);
#pragma unroll
    for (int mf = 0; mf < 4; ++mf)
#pragma unroll
      for (int nf = 0; nf < 4; ++nf)
#pragma unroll
        for (int ks = 0; ks < 2; ++ks)
          acc[mf][nf] = __builtin_amdgcn_mfma_f32_16x16x32_bf16(
              af[mf][ks], bfr[nf][ks], acc[mf][nf], 0, 0, 0);
    __builtin_amdgcn_s_setprio(0);
  }

  // epilogue: per-wave 64x68 f32 tile in LDS -> float4 stores
  __syncthreads();
  float* ep = (float*)smem + (size_t)w * (64 * 68);
  const int crow = (l >> 4) * 4;
#pragma unroll
  for (int mf = 0; mf < 4; ++mf)
#pragma unroll
    for (int nf = 0; nf < 4; ++nf)
#pragma unroll
      for (int r = 0; r < 4; ++r)
        ep[(mf * 16 + crow + r) * 68 + nf * 16 + fr] = acc[mf][nf][r];
#pragma unroll
  for (int it = 0; it < 16; ++it) {
    const int row = it * 4 + (l >> 4);
    const int c4 = (l & 15) * 4;
    const float4 v4 = *(const float4*)&ep[row * 68 + c4];
    *(float4*)(Cm + (size_t)(m0 + wm * 64 + row) * 2048 + n0 + wn * 64 + c4) = v4;
  }
#undef STAGE_AW
#undef STAGE_BW
#undef LDA_FRAGW
#undef LDB_FRAGW
}

// ---------------------------------------------------------------------------
// fused causal dwconv(K=4)+silu + (k,v) transpose.
// grid (TT/64, CC/64, 3*BB): which = z/BB (0:q 1:k 2:v), b = z%BB.
// ---------------------------------------------------------------------------
__global__ __launch_bounds__(256)
void conv_tr(const __bf16* __restrict__ u_q, const __bf16* __restrict__ u_k,
             const __bf16* __restrict__ u_v, const float* __restrict__ wq,
             const float* __restrict__ wk, const float* __restrict__ wv,
             __bf16* __restrict__ qbf, __bf16* __restrict__ kbf,
             __bf16* __restrict__ kT, __bf16* __restrict__ vT, float qscale)
{
  const int t0 = blockIdx.x * 64, c0 = blockIdx.y * 64;
  const int which = blockIdx.z / BB, b = blockIdx.z % BB;
  const __bf16* u = which == 0 ? u_q : which == 1 ? u_k : u_v;
  const float* wc = which == 0 ? wq : which == 1 ? wk : wv;
  const float scale = which == 0 ? qscale : 1.f;
  const int tid = threadIdx.x;
  __shared__ __attribute__((aligned(16))) __bf16 tile[64][72];

#pragma unroll
  for (int it = 0; it < 2; ++it) {
    const int idx = tid + it * 256;
    const int tl = idx >> 3, g = idx & 7;
    const int t = t0 + tl;
    const int c8 = c0 + g * 8;
    const size_t base = ((size_t)(b * TT + t)) * CC + c8;
    const bf16x8 z = {};
    const bf16x8 uu0 = *(const bf16x8*)(u + base);
    const bf16x8 uu1 = (t >= 1) ? *(const bf16x8*)(u + base - CC)     : z;
    const bf16x8 uu2 = (t >= 2) ? *(const bf16x8*)(u + base - 2 * CC) : z;
    const bf16x8 uu3 = (t >= 3) ? *(const bf16x8*)(u + base - 3 * CC) : z;
    bf16x8 o;
#pragma unroll
    for (int jj = 0; jj < 8; ++jj) {
      const float4 wv4 = *(const float4*)(wc + (size_t)(c8 + jj) * 4);
      const float vv = wv4.x * (float)uu3[jj] + wv4.y * (float)uu2[jj]
                     + wv4.z * (float)uu1[jj] + wv4.w * (float)uu0[jj];
      o[jj] = (__bf16)(vv / (1.f + expf(-vv)) * scale);
    }
    if (which == 0) *(bf16x8*)(qbf + base) = o;
    if (which == 1) *(bf16x8*)(kbf + base) = o;
    if (which >= 1) *(bf16x8*)&tile[tl][g * 8] = o;
  }
  if (which >= 1) {
    __syncthreads();
    const int h = c0 >> 7, d0 = c0 & 127;
    const int bh = b * HH + h;
    __bf16* dst = (which == 1) ? kT : vT;
#pragma unroll
    for (int it = 0; it < 2; ++it) {
      const int idx = tid + it * 256;
      const int dl = idx >> 3, g = idx & 7;
      bf16x8 o;
#pragma unroll
      for (int jj = 0; jj < 8; ++jj) o[jj] = tile[g * 8 + jj][dl];
      *(bf16x8*)(dst + ((size_t)(bh * DD + d0 + dl)) * TT + t0 + g * 8) = o;
    }
  }
}

// ---------------------------------------------------------------------------
// Phase A (MFMA): contribT[e][d] = sum_s (w_s k_s[d]) v_s[e];  decay out.
// ---------------------------------------------------------------------------
__global__ __launch_bounds__(256)
void phaseA_mfma(const __bf16* __restrict__ kT, const __bf16* __restrict__ vT,
                 const float* __restrict__ beta, float* __restrict__ contribT,
                 float* __restrict__ decay)
{
  const int c = blockIdx.x, h = blockIdx.y, b = blockIdx.z;
  const int bh = b * HH + h;
  const int tid = threadIdx.x;
  const int w = tid >> 6, lane = tid & 63;
  const int wm = w >> 1, wn = w & 1;

  __shared__ __attribute__((aligned(16))) __bf16 bufVT[128 * 128];
  __shared__ __attribute__((aligned(16))) __bf16 bufKW[128 * 128];
  __shared__ float lc[CHUNK], bsh[CHUNK], wgt[CHUNK];

  {
    const __bf16* vbase = vT + ((size_t)bh * DD) * TT + c * CHUNK;
#pragma unroll
    for (int jj = 0; jj < 8; ++jj) {
      const int row = w * 32 + jj * 4 + (lane >> 4);
      const int g = lane & 15;
      GLD16(vbase + (size_t)row * TT + ((g ^ (row & 7)) << 3),
            bufVT + (w * 32 + jj * 4) * 128);
    }
  }

  if (tid < CHUNK) {
    const float bv = beta[(size_t)(b * TT + c * CHUNK + tid) * HH + h];
    bsh[tid] = bv;
    lc[tid] = log1pf(-bv);
  }
  __syncthreads();
  for (int off = 1; off < CHUNK; off <<= 1) {
    float add = 0.f;
    if (tid < CHUNK && tid >= off) add = lc[tid - off];
    __syncthreads();
    if (tid < CHUNK) lc[tid] += add;
    __syncthreads();
  }
  const float lend = lc[CHUNK - 1];
  if (tid < CHUNK) wgt[tid] = bsh[tid] * expf(lend - lc[tid]);
  if (tid == 0) decay[(size_t)bh * NC + c] = expf(lend);
  __syncthreads();

  {
    const __bf16* kbase = kT + ((size_t)bh * DD) * TT + c * CHUNK;
#pragma unroll
    for (int it = 0; it < 8; ++it) {
      const int idx = tid + it * 256;
      const int d = idx >> 4, g = idx & 15;
      const bf16x8 kv = *(const bf16x8*)(kbase + (size_t)d * TT + g * 8);
      bf16x8 o;
#pragma unroll
      for (int jj = 0; jj < 8; ++jj)
        o[jj] = (__bf16)((float)kv[jj] * wgt[g * 8 + jj]);
      *(bf16x8*)(bufKW + d * 128 + ((g ^ (d & 7)) << 3)) = o;
    }
  }
  asm volatile("s_waitcnt vmcnt(0)" ::: "memory");
  __syncthreads();

  f32x4 acc[4][4] = {};
#pragma unroll
  for (int ks = 0; ks < 4; ++ks) {
    bf16x8 a[4], bq[4];
    const int kg = ks * 4 + (lane >> 4);
#pragma unroll
    for (int f = 0; f < 4; ++f) a[f]  = ldfrag(bufVT, wm * 64 + f * 16 + (lane & 15), kg);
#pragma unroll
    for (int f = 0; f < 4; ++f) bq[f] = ldfrag(bufKW, wn * 64 + f * 16 + (lane & 15), kg);
#pragma unroll
    for (int i = 0; i < 4; ++i)
#pragma unroll
      for (int j = 0; j < 4; ++j)
        acc[i][j] = __builtin_amdgcn_mfma_f32_16x16x32_bf16(a[i], bq[j], acc[i][j], 0, 0, 0);
  }

  float* cp = contribT + ((size_t)(bh * NC + c) << 14);
  const int crow = (lane >> 4) * 4;
#pragma unroll
  for (int i = 0; i < 4; ++i)
#pragma unroll
    for (int j = 0; j < 4; ++j) {
      const int dd = wn * 64 + j * 16 + (lane & 15);
#pragma unroll
      for (int r = 0; r < 4; ++r) {
        const int e = wm * 64 + i * 16 + crow + r;
        cp[(size_t)e * 128 + dd] = acc[i][j][r];
      }
    }
}

// ---------------------------------------------------------------------------
// Phase B: absorbs both state transposes. st0/stOut are (B,H,D,D) [d][e];
// internal pipeline runs in [e][d] space (coalesced contrib/states access).
// ---------------------------------------------------------------------------
__global__ __launch_bounds__(256)
void phaseB_T(const float* __restrict__ st0, const float* __restrict__ contribT,
              const float* __restrict__ decay, __bf16* __restrict__ statesT,
              float* __restrict__ stOut)
{
  const size_t gid = (size_t)blockIdx.x * 256 + threadIdx.x;
  const int bh = (int)(gid >> 14);
  const int ed = (int)(gid & 16383);
  const int e = ed >> 7, d = ed & 127;
  const size_t tidx = ((size_t)bh << 14) + (size_t)d * 128 + e;
  float s = st0[tidx];
  const float* dc = decay + (size_t)bh * NC;
#pragma unroll
  for (int c = 0; c < NC; ++c) {
    const size_t off = ((size_t)(bh * NC + c) << 14) + ed;
    statesT[off] = (__bf16)s;
    s = fmaf(dc[c], s, contribT[off]);
  }
  stOut[tidx] = s;
}

// ---------------------------------------------------------------------------
// Phase C (MFMA) + fused GroupNorm partial stats.
// ---------------------------------------------------------------------------
__global__ __launch_bounds__(256)
void phaseC_mfma(const __bf16* __restrict__ qb, const __bf16* __restrict__ kb,
                 const __bf16* __restrict__ vT, const float* __restrict__ beta,
                 const __bf16* __restrict__ statesT, float* __restrict__ att,
                 float* __restrict__ partials)
{
  const int c = blockIdx.x, h = blockIdx.y, b = blockIdx.z;
  const int bh = b * HH + h;
  const int tid = threadIdx.x;
  const int w = tid >> 6, lane = tid & 63;
  const int wm = w >> 1, wn = w & 1;

  __shared__ __attribute__((aligned(16))) __bf16 bufQ[128 * 128];
  __shared__ __attribute__((aligned(16))) __bf16 bufB[128 * 128];
  __shared__ float lc[CHUNK], bsh[CHUNK];
  __shared__ float s1[256], s2[256];

  {
    const __bf16* qbase = qb + ((size_t)(b * TT + c * CHUNK)) * CC + h * DD;
    const __bf16* kbase = kb + ((size_t)(b * TT + c * CHUNK)) * CC + h * DD;
#pragma unroll
    for (int jj = 0; jj < 8; ++jj) {
      const int row = w * 32 + jj * 4 + (lane >> 4);
      const int g = lane & 15;
      GLD16(qbase + (size_t)row * CC + ((g ^ (row & 7)) << 3),
            bufQ + (w * 32 + jj * 4) * 128);
      GLD16(kbase + (size_t)row * CC + ((g ^ (row & 7)) << 3),
            bufB + (w * 32 + jj * 4) * 128);
    }
  }

  if (tid < CHUNK) {
    const float bv = beta[(size_t)(b * TT + c * CHUNK + tid) * HH + h];
    bsh[tid] = bv;
    lc[tid] = log1pf(-bv);
  }
  __syncthreads();
  for (int off = 1; off < CHUNK; off <<= 1) {
    float add = 0.f;
    if (tid < CHUNK && tid >= off) add = lc[tid - off];
    __syncthreads();
    if (tid < CHUNK) lc[tid] += add;
    __syncthreads();
  }

  asm volatile("s_waitcnt vmcnt(0)" ::: "memory");
  __syncthreads();

  // S = Q K^T
  f32x4 accS[4][4] = {};
#pragma unroll
  for (int ks = 0; ks < 4; ++ks) {
    bf16x8 a[4], bq[4];
    const int kg = ks * 4 + (lane >> 4);
#pragma unroll
    for (int f = 0; f < 4; ++f) a[f]  = ldfrag(bufQ, wm * 64 + f * 16 + (lane & 15), kg);
#pragma unroll
    for (int f = 0; f < 4; ++f) bq[f] = ldfrag(bufB, wn * 64 + f * 16 + (lane & 15), kg);
#pragma unroll
    for (int i = 0; i < 4; ++i)
#pragma unroll
      for (int j = 0; j < 4; ++j)
        accS[i][j] = __builtin_amdgcn_mfma_f32_16x16x32_bf16(a[i], bq[j], accS[i][j], 0, 0, 0);
  }

  __syncthreads();
  {
    const __bf16* sbase = statesT + ((size_t)(bh * NC + c) << 14);
#pragma unroll
    for (int jj = 0; jj < 8; ++jj) {
      const int row = w * 32 + jj * 4 + (lane >> 4);
      const int g = lane & 15;
      GLD16(sbase + (size_t)row * 128 + ((g ^ (row & 7)) << 3),
            bufB + (w * 32 + jj * 4) * 128);
    }
  }
  asm volatile("s_waitcnt vmcnt(0)" ::: "memory");
  __syncthreads();

  // accO = Q S0T, scaled by e^{lc_t}
  f32x4 accO[4][4] = {};
#pragma unroll
  for (int ks = 0; ks < 4; ++ks) {
    bf16x8 a[4], bq[4];
    const int kg = ks * 4 + (lane >> 4);
#pragma unroll
    for (int f = 0; f < 4; ++f) a[f]  = ldfrag(bufQ, wm * 64 + f * 16 + (lane & 15), kg);
#pragma unroll
    for (int f = 0; f < 4; ++f) bq[f] = ldfrag(bufB, wn * 64 + f * 16 + (lane & 15), kg);
#pragma unroll
    for (int i = 0; i < 4; ++i)
#pragma unroll
      for (int j = 0; j < 4; ++j)
        accO[i][j] = __builtin_amdgcn_mfma_f32_16x16x32_bf16(a[i], bq[j], accO[i][j], 0, 0, 0);
  }
  const int crow = (lane >> 4) * 4;
#pragma unroll
  for (int i = 0; i < 4; ++i)
#pragma unroll
    for (int r = 0; r < 4; ++r) {
      const float el = expf(lc[wm * 64 + i * 16 + crow + r]);
#pragma unroll
      for (int j = 0; j < 4; ++j) accO[i][j][r] *= el;
    }

  __syncthreads();
  {
    const __bf16* vbase = vT + ((size_t)bh * DD) * TT + c * CHUNK;
#pragma unroll
    for (int jj = 0; jj < 8; ++jj) {
      const int row = w * 32 + jj * 4 + (lane >> 4);
      const int g = lane & 15;
      GLD16(vbase + (size_t)row * TT + ((g ^ (row & 7)) << 3),
            bufB + (w * 32 + jj * 4) * 128);
    }
  }
  {
    float lcs[4], bss[4];
#pragma unroll
    for (int j = 0; j < 4; ++j) {
      const int s = wn * 64 + j * 16 + (lane & 15);
      lcs[j] = lc[s]; bss[j] = bsh[s];
    }
#pragma unroll
    for (int i = 0; i < 4; ++i)
#pragma unroll
      for (int r = 0; r < 4; ++r) {
        const int t = wm * 64 + i * 16 + crow + r;
        const float lct = lc[t];
#pragma unroll
        for (int j = 0; j < 4; ++j) {
          const int s = wn * 64 + j * 16 + (lane & 15);
          float p = 0.f;
          if (s <= t) p = accS[i][j][r] * bss[j] * expf(lct - lcs[j]);
          bufQ[t * 128 + (((s >> 3) ^ (t & 7)) << 3) + (s & 7)] = (__bf16)p;
        }
      }
  }
  asm volatile("s_waitcnt vmcnt(0)" ::: "memory");
  __syncthreads();

  // accO += P V^T
#pragma unroll
  for (int ks = 0; ks < 4; ++ks) {
    bf16x8 a[4], bq[4];
    const int kg = ks * 4 + (lane >> 4);
#pragma unroll
    for (int f = 0; f < 4; ++f) a[f]  = ldfrag(bufQ, wm * 64 + f * 16 + (lane & 15), kg);
#pragma unroll
    for (int f = 0; f < 4; ++f) bq[f] = ldfrag(bufB, wn * 64 + f * 16 + (lane & 15), kg);
#pragma unroll
    for (int i = 0; i < 4; ++i)
#pragma unroll
      for (int j = 0; j < 4; ++j)
        accO[i][j] = __builtin_amdgcn_mfma_f32_16x16x32_bf16(a[i], bq[j], accO[i][j], 0, 0, 0);
  }

  // epilogue: store att + accumulate GN partial stats
  float lsum = 0.f, lsq = 0.f;
  float* obase = att + ((size_t)(b * TT + c * CHUNK)) * CC + h * DD;
#pragma unroll
  for (int i = 0; i < 4; ++i)
#pragma unroll
    for (int j = 0; j < 4; ++j) {
      const int e = wn * 64 + j * 16 + (lane & 15);
#pragma unroll
      for (int r = 0; r < 4; ++r) {
        const int t = wm * 64 + i * 16 + crow + r;
        const float vv = accO[i][j][r];
        obase[(size_t)t * CC + e] = vv;
        lsum += vv;
        lsq  += vv * vv;
      }
    }
  s1[tid] = lsum; s2[tid] = lsq;
  __syncthreads();
  for (int off = 128; off; off >>= 1) {
    if (tid < off) { s1[tid] += s1[tid + off]; s2[tid] += s2[tid + off]; }
    __syncthreads();
  }
  if (tid == 0) {
    partials[(size_t)(bh * NC + c) * 2]     = s1[0];
    partials[(size_t)(bh * NC + c) * 2 + 1] = s2[0];
  }
}

// ---------------------------------------------------------------------------
// normalize + gate -> bf16; absorbs GN partial combine (8 heads per block).
// ---------------------------------------------------------------------------
__global__ __launch_bounds__(256)
void norm_gate(const float* __restrict__ att, const __bf16* __restrict__ gate,
               const float* __restrict__ partials, __bf16* __restrict__ g)
{
  __shared__ float sm[8], sr[8];
  const int tid = threadIdx.x;
  const size_t gid0 = (size_t)blockIdx.x * 1024;
  const int b = (int)(gid0 >> 22);
  const int h0 = ((int)(gid0 & 2047)) >> 7;     // 0 or 8
  if (tid < 8) {
    const int bh = b * HH + h0 + tid;
    float s = 0.f, q = 0.f;
#pragma unroll
    for (int cc = 0; cc < NC; ++cc) {
      s += partials[(size_t)(bh * NC + cc) * 2];
      q += partials[(size_t)(bh * NC + cc) * 2 + 1];
    }
    const float n = (float)(TT * DD);
    const float mean = s / n;
    sm[tid] = mean;
    sr[tid] = rsqrtf(q / n - mean * mean + GN_EPS);
  }
  __syncthreads();
  const size_t gid = gid0 + (size_t)tid * 4;
  const int hl = (tid * 4) >> 7;                // 0..7
  const float mean = sm[hl], rstd = sr[hl];
  const float4 a = *(const float4*)(att + gid);
  const bf16x4 gt = *(const bf16x4*)(gate + gid);
  bf16x4 o;
  o[0] = (__bf16)((a.x - mean) * rstd * (float)gt[0]);
  o[1] = (__bf16)((a.y - mean) * rstd * (float)gt[1]);
  o[2] = (__bf16)((a.z - mean) * rstd * (float)gt[2]);
  o[3] = (__bf16)((a.w - mean) * rstd * (float)gt[3]);
  *(bf16x4*)(g + gid) = o;
}

// ---------------------------------------------------------------------------
extern "C" void kernel_launch(void* const* d_in, const int* in_sizes, int n_in,
                              void* d_out, int out_size, void* d_ws, size_t ws_size,
                              hipStream_t stream)
{
  const float* x      = (const float*)d_in[0];
  const float* st0    = (const float*)d_in[1];
  const float* Wq     = (const float*)d_in[2];
  const float* Wk     = (const float*)d_in[3];
  const float* Wv     = (const float*)d_in[4];
  const float* Wbeta  = (const float*)d_in[5];
  const float* Wgate  = (const float*)d_in[6];
  const float* Wo     = (const float*)d_in[7];
  const float* wqc    = (const float*)d_in[8];
  const float* wkc    = (const float*)d_in[9];
  const float* wvc    = (const float*)d_in[10];

  float* ws = (float*)d_ws;
  __bf16* qbf  = (__bf16*)(ws + 0);           // 8.4M bf16
  __bf16* kbf  = (__bf16*)(ws + 4194304);     // 8.4M bf16
  __bf16* u_v  = (__bf16*)(ws + 8388608);     // pre-act v; -> statesT after conv
  __bf16* statesT = (__bf16*)(ws + 8388608);  // (phaseB; u_v dead by then)
  __bf16* kT   = (__bf16*)(ws + 12582912);    // -> gbf after phaseC
  __bf16* gbf  = (__bf16*)(ws + 12582912);
  __bf16* vT   = (__bf16*)(ws + 16777216);
  __bf16* xbf  = (__bf16*)(ws + 20971520);    // dead after gemm_big
  float* contribT = ws + 20971520;            // 8.4M f, overlays xbf + Wcat[0:4.2M]
  __bf16* Wcat = (__bf16*)(ws + 25165824);    // 16.8M bf16 (8192x2048), dead after gemm_big
  __bf16* gatebuf = (__bf16*)(ws + 33554432); // 8.4M bf16, alive GEMM -> norm_gate
  float* betab    = ws + 37748736;            // 65536
  float* decay    = ws + 37814272;            // 512
  float* partials = ws + 37814848;            // 1024
  __bf16* Wob  = (__bf16*)(ws + 38864448);    // 4.2M bf16

  float* y_out  = (float*)d_out;
  float* st_out = (float*)d_out + (size_t)BB * TT * EE;
  __bf16* u_q = (__bf16*)d_out;               // bf16 [0, 8388608)
  __bf16* u_k = (__bf16*)d_out + 8388608;     // bf16 [8388608, 16777216)
  float* att = y_out;

  const dim3 blk(256);
  const dim3 gBig(8192 / 256, (BB * TT) / 256);    // 32 x 16 = 512 blocks
  const dim3 gWo(EE / 256, (BB * TT) / 128);       // 8 x 32 = 256 blocks
  const dim3 gConv(TT / 64, CC / 64, 3 * BB);      // 32 x 32 x 6
  const dim3 gScan(NC, HH, BB);
  const float qscale = 0.08838834764831845f;

  // all f32->bf16 conversions in one launch
  convert_all<<<dim3(28672), blk, 0, stream>>>(x, Wq, Wk, Wv, Wgate, Wo,
                                               xbf, Wcat, Wob);

  // beta (fp32)
  beta_ker<<<dim3((BB * TT) / 4), blk, 0, stream>>>(x, Wbeta, betab);

  // merged QKV+gate projection (256^2, 8-phase m201-template pipelined)
  gemm_big<<<gBig, dim3(512), 0, stream>>>(xbf, Wcat, u_q, u_k, u_v, gatebuf);

  // conv/silu + k,v transposes, fused
  conv_tr<<<gConv, blk, 0, stream>>>(u_q, u_k, u_v, wqc, wkc, wvc,
                                     qbf, kbf, kT, vT, qscale);

  // chunked delta scan (MFMA); phaseB absorbs the state transposes
  phaseA_mfma<<<gScan, blk, 0, stream>>>(kT, vT, betab, contribT, decay);
  phaseB_T<<<dim3((BB * HH * DD * DD) / 256), blk, 0, stream>>>(st0, contribT, decay, statesT, st_out);
  phaseC_mfma<<<gScan, blk, 0, stream>>>(qbf, kbf, vT, betab, statesT, att, partials);

  // groupnorm (combine fused) + gate -> bf16
  norm_gate<<<dim3((BB * TT * CC) / 1024), blk, 0, stream>>>(att, gatebuf, partials, gbf);

  // y = g @ Wo^T (1-phase pipelined 128x256 structure, 256 blocks)
  gemm_wo<<<gWo, dim3(512), 0, stream>>>(gbf, Wob, y_out);
}

// Round 11
// 334.826 us; speedup vs baseline: 1.0031x; 1.0031x over previous
//
#include <hip/hip_runtime.h>
#include <hip/hip_bf16.h>
#include <math.h>

#define BB 2
#define TT 2048
#define EE 2048
#define HH 16
#define DD 128
#define CC 2048
#define KCONV 4
#define CHUNK 128
#define NC 16          // TT / CHUNK
#define GN_EPS 1e-5f

typedef __bf16 bf16x8 __attribute__((ext_vector_type(8)));
typedef __bf16 bf16x4 __attribute__((ext_vector_type(4)));
typedef float  f32x4  __attribute__((ext_vector_type(4)));

#define GLD16(gp, lp)                                                          \
  __builtin_amdgcn_global_load_lds(                                            \
      (const __attribute__((address_space(1))) void*)(gp),                     \
      (__attribute__((address_space(3))) void*)(lp), 16, 0, 0)

// swizzled fragment load: row-major [128][128] bf16 tile, 16B-group XOR swizzle
__device__ __forceinline__ bf16x8 ldfrag(const __bf16* buf, int row, int kg)
{
  return *(const bf16x8*)(buf + row * 128 + ((kg ^ (row & 7)) << 3));
}

// ---------------------------------------------------------------------------
// f32 -> bf16 conversion for Wq|Wk|Wv|Wgate (into Wcat) and Wo.
// 20,971,520 elems, 4/thread -> 20480 blocks.
// ---------------------------------------------------------------------------
__global__ __launch_bounds__(256)
void convert_w(const float* __restrict__ Wq, const float* __restrict__ Wk,
               const float* __restrict__ Wv, const float* __restrict__ Wg,
               const float* __restrict__ Wo, __bf16* __restrict__ Wcat,
               __bf16* __restrict__ Wob)
{
  const int i = (blockIdx.x * 256 + threadIdx.x) * 4;
  const int WN = 4194304;
  const float* src;
  __bf16* dst;
  int off;
  if (i < 4 * WN) {
    const int seg = i >> 22;
    src = seg == 0 ? Wq : seg == 1 ? Wk : seg == 2 ? Wv : Wg;
    dst = Wcat + ((size_t)seg << 22);
    off = i & (WN - 1);
  } else { src = Wo; dst = Wob; off = i - 4 * WN; }
  const float4 v = *(const float4*)(src + off);
  bf16x4 o;
  o[0] = (__bf16)v.x; o[1] = (__bf16)v.y; o[2] = (__bf16)v.z; o[3] = (__bf16)v.w;
  *(bf16x4*)(dst + off) = o;
}

// ---------------------------------------------------------------------------
// beta = sigmoid(x @ Wbeta^T)  AND emits xbf (x rows are read here anyway).
// ---------------------------------------------------------------------------
__global__ __launch_bounds__(256)
void beta_ker(const float* __restrict__ x, const float* __restrict__ Wb,
              float* __restrict__ betab, __bf16* __restrict__ xbf)
{
  __shared__ float wsb[16 * 1024];   // 64 KB
  const int tid = threadIdx.x;
  const int w = tid >> 6, lane = tid & 63;
  const int row = blockIdx.x * 4 + w;           // < B*T = 4096
  const float* xrow = x + (size_t)row * EE;
  __bf16* xbrow = xbf + (size_t)row * EE;

  float acc[16] = {};
#pragma unroll
  for (int kt = 0; kt < 2; ++kt) {
    __syncthreads();
#pragma unroll
    for (int it = 0; it < 16; ++it) {
      const int i = tid + it * 256;
      const int h = i >> 8, kq = i & 255;
      *(float4*)&wsb[h * 1024 + kq * 4] =
          *(const float4*)(Wb + (size_t)h * EE + kt * 1024 + kq * 4);
    }
    __syncthreads();
#pragma unroll
    for (int j = 0; j < 4; ++j) {
      const int kof = lane * 4 + j * 256;
      const float4 xv = *(const float4*)(xrow + kt * 1024 + kof);
      bf16x4 xb;
      xb[0] = (__bf16)xv.x; xb[1] = (__bf16)xv.y;
      xb[2] = (__bf16)xv.z; xb[3] = (__bf16)xv.w;
      *(bf16x4*)(xbrow + kt * 1024 + kof) = xb;
#pragma unroll
      for (int h = 0; h < 16; ++h) {
        const float4 wv = *(const float4*)&wsb[h * 1024 + kof];
        acc[h] += xv.x * wv.x + xv.y * wv.y + xv.z * wv.z + xv.w * wv.w;
      }
    }
  }
#pragma unroll
  for (int h = 0; h < 16; ++h) {
#pragma unroll
    for (int off = 32; off; off >>= 1)
      acc[h] += __shfl_xor(acc[h], off, 64);
  }
#pragma unroll
  for (int h = 0; h < 16; ++h)
    if (lane == h)
      betab[(size_t)row * HH + h] = 1.f / (1.f + expf(-acc[h]));
}

// ---------------------------------------------------------------------------
// 256x256 deep-pipelined bf16 GEMM (QKV+gate merged), K=2048, BK=64.
// 8 waves (2Mx4N). LDS = 3 A-bufs + 2 B-bufs = 160 KiB. ONE barrier/phase
// (round-8 proven schedule). XCD-aware column-chunked block swizzle: each
// XCD owns 4 contiguous B col-panels (4MB, L2-resident) and streams A.
// ---------------------------------------------------------------------------
__global__ __launch_bounds__(512)
void gemm_big(const __bf16* __restrict__ A, const __bf16* __restrict__ Bm,
              __bf16* __restrict__ o0, __bf16* __restrict__ o1,
              __bf16* __restrict__ o2, __bf16* __restrict__ o3)
{
  __shared__ __attribute__((aligned(16))) unsigned char smem[163840];
  __bf16 (*ldsA)[256 * 64] = (__bf16(*)[256 * 64])smem;             // 3 x 32KB
  __bf16 (*ldsB)[256 * 64] = (__bf16(*)[256 * 64])(smem + 98304);   // 2 x 32KB

  const int tid = threadIdx.x;
  const int w = tid >> 6, l = tid & 63;
  const int wm = w >> 2, wn = w & 3;          // 2 x 4 wave grid
  // XCD swizzle: orig (x-fastest, 32 wide) -> column-major chunks of 64/XCD
  const int orig = blockIdx.x + (blockIdx.y << 5);        // nwg = 512
  const int swz = (orig & 7) * 64 + (orig >> 3);
  const int m0 = (swz & 15) * 256, n0 = (swz >> 4) * 256;
  const int NT = EE / 64;                     // 32 K-tiles

  const int sr0 = w * 8 + (l >> 3);           // staging dest row, 0..63
  const int skg = l & 7;                      // dest 16B chunk in 128B row
  const int fr = l & 15;
  const int fkg = l >> 4;                     // 0..3

#define STAGE_A(tile, half) do {                                               \
    const int b_ = (tile) % 3;                                                 \
    const int r0_ = sr0;                                                       \
    const int r1_ = 64 + sr0;                                                  \
    GLD16(A + (size_t)(m0 + (half) * 128 + r0_) * 2048 + (tile) * 64           \
              + ((skg ^ (r0_ & 7)) << 3),                                      \
          ldsA[b_] + ((half) * 128 + w * 8) * 64);                             \
    GLD16(A + (size_t)(m0 + (half) * 128 + r1_) * 2048 + (tile) * 64           \
              + ((skg ^ (r1_ & 7)) << 3),                                      \
          ldsA[b_] + ((half) * 128 + 64 + w * 8) * 64);                        \
  } while (0)

#define STAGE_B(tile, half) do {                                               \
    const int b_ = (tile) & 1;                                                 \
    const int r0_ = sr0;                                                       \
    const int r1_ = 64 + sr0;                                                  \
    GLD16(Bm + (size_t)(n0 + (half) * 128 + r0_) * 2048 + (tile) * 64          \
              + ((skg ^ (r0_ & 7)) << 3),                                      \
          ldsB[b_] + ((half) * 128 + w * 8) * 64);                             \
    GLD16(Bm + (size_t)(n0 + (half) * 128 + r1_) * 2048 + (tile) * 64          \
              + ((skg ^ (r1_ & 7)) << 3),                                      \
          ldsB[b_] + ((half) * 128 + 64 + w * 8) * 64);                        \
  } while (0)

#define LDA_FRAG(dst, ab, q, mf, ks) do {                                      \
    const int row_ = wm * 128 + (q) * 32 + (mf) * 16 + fr;                     \
    const int kg_ = (ks) * 4 + fkg;                                            \
    dst = *(const bf16x8*)&ldsA[ab][row_ * 64 + ((kg_ ^ (row_ & 7)) << 3)];    \
  } while (0)
#define LDB_FRAG(dst, bb, nf, ks) do {                                         \
    const int row_ = wn * 64 + (nf) * 16 + fr;                                 \
    const int kg_ = (ks) * 4 + fkg;                                            \
    dst = *(const bf16x8*)&ldsB[bb][row_ * 64 + ((kg_ ^ (row_ & 7)) << 3)];    \
  } while (0)

  f32x4 acc[8][4] = {};

  // prologue: 14 loads; tile 0 resident after vmcnt(6)+barrier.
  STAGE_A(0, 0); STAGE_A(0, 1); STAGE_B(0, 0); STAGE_B(0, 1);
  STAGE_A(1, 0); STAGE_A(1, 1); STAGE_B(1, 0);
  asm volatile("s_waitcnt vmcnt(6)" ::: "memory");
  __builtin_amdgcn_s_barrier();

  for (int t = 0; t < NT; ++t) {
    const int abuf = t % 3;
    const int bbuf = t & 1;
    bf16x8 bfr[4][2];

    // ---- phase q0: all B frags + A quadrant 0; stage B(t+1,1)
    {
      bf16x8 af[2][2];
#pragma unroll
      for (int nf = 0; nf < 4; ++nf)
#pragma unroll
        for (int ks = 0; ks < 2; ++ks) LDB_FRAG(bfr[nf][ks], bbuf, nf, ks);
#pragma unroll
      for (int mf = 0; mf < 2; ++mf)
#pragma unroll
        for (int ks = 0; ks < 2; ++ks) LDA_FRAG(af[mf][ks], abuf, 0, mf, ks);
      if (t + 1 < NT) STAGE_B(t + 1, 1);
      __builtin_amdgcn_s_barrier();
      __builtin_amdgcn_s_setprio(1);
#pragma unroll
      for (int mf = 0; mf < 2; ++mf)
#pragma unroll
        for (int nf = 0; nf < 4; ++nf)
#pragma unroll
          for (int ks = 0; ks < 2; ++ks)
            acc[mf][nf] = __builtin_amdgcn_mfma_f32_16x16x32_bf16(
                af[mf][ks], bfr[nf][ks], acc[mf][nf], 0, 0, 0);
      __builtin_amdgcn_s_setprio(0);
    }

    // ---- phases q1..q3 (one barrier each)
#pragma unroll
    for (int q = 1; q < 4; ++q) {
      bf16x8 af[2][2];
#pragma unroll
      for (int mf = 0; mf < 2; ++mf)
#pragma unroll
        for (int ks = 0; ks < 2; ++ks) LDA_FRAG(af[mf][ks], abuf, q, mf, ks);
      if (q == 1) {
        if (t + 2 < NT) STAGE_A(t + 2, 0);
      } else if (q == 2) {
        if (t + 2 < NT) STAGE_A(t + 2, 1);
      } else {
        if (t + 2 < NT) STAGE_B(t + 2, 0);
        if (t == NT - 2)     asm volatile("s_waitcnt vmcnt(0)" ::: "memory");
        else if (t < NT - 2) asm volatile("s_waitcnt vmcnt(6)" ::: "memory");
      }
      __builtin_amdgcn_s_barrier();
      __builtin_amdgcn_s_setprio(1);
#pragma unroll
      for (int mf = 0; mf < 2; ++mf)
#pragma unroll
        for (int nf = 0; nf < 4; ++nf)
#pragma unroll
          for (int ks = 0; ks < 2; ++ks)
            acc[2 * q + mf][nf] = __builtin_amdgcn_mfma_f32_16x16x32_bf16(
                af[mf][ks], bfr[nf][ks], acc[2 * q + mf][nf], 0, 0, 0);
      __builtin_amdgcn_s_setprio(0);
    }
  }

  // epilogue through LDS: per-wave 128x72 padded tile, coalesced bf16x8 stores
  __syncthreads();
  const int proj = n0 >> 11;
  const int nb = n0 & 2047;
  __bf16* outp = proj == 0 ? o0 : proj == 1 ? o1 : proj == 2 ? o2 : o3;
  __bf16* ep = (__bf16*)smem + (size_t)w * 9216;
  const int crow = (l >> 4) * 4;
#pragma unroll
  for (int mf2 = 0; mf2 < 8; ++mf2)
#pragma unroll
    for (int nf = 0; nf < 4; ++nf)
#pragma unroll
      for (int r = 0; r < 4; ++r) {
        const int row = mf2 * 16 + crow + r;
        float vv = acc[mf2][nf][r];
        if (proj == 3) vv = 1.f / (1.f + expf(-vv));
        ep[row * 72 + nf * 16 + fr] = (__bf16)vv;
      }
#pragma unroll
  for (int it = 0; it < 16; ++it) {
    const int row = it * 8 + (l >> 3);
    const int c8 = (l & 7) * 8;
    const bf16x8 v8 = *(const bf16x8*)&ep[row * 72 + c8];
    *(bf16x8*)(outp + (size_t)(m0 + wm * 128 + row) * 2048 + nb + wn * 64 + c8) = v8;
  }
#undef STAGE_A
#undef STAGE_B
#undef LDA_FRAG
#undef LDB_FRAG
}

// ---------------------------------------------------------------------------
// Wo GEMM, pipelined: BM=128 x BN=256, 256 blocks (1/CU), XCD swizzle:
// each XCD owns one Wo col-panel (1MB, L2-resident).
// ONE phase per K-tile: vmcnt -> barrier -> reads -> stages(t+2) -> 32 MFMA.
// ---------------------------------------------------------------------------
__global__ __launch_bounds__(512)
void gemm_wo(const __bf16* __restrict__ A, const __bf16* __restrict__ Bm,
             float* __restrict__ Cm)
{
  __shared__ __attribute__((aligned(16))) unsigned char smem[147456];
  __bf16 (*ldsA)[128 * 64] = (__bf16(*)[128 * 64])smem;              // 3 x 16KB
  __bf16 (*ldsB)[256 * 64] = (__bf16(*)[256 * 64])(smem + 49152);    // 3 x 32KB

  const int tid = threadIdx.x;
  const int w = tid >> 6, l = tid & 63;
  const int wm = w >> 2, wn = w & 3;
  // XCD swizzle: nwg = 256, grid (8, 32), x fastest
  const int orig = blockIdx.x + (blockIdx.y << 3);
  const int swz = (orig & 7) * 32 + (orig >> 3);
  const int m0 = (swz & 31) * 128, n0 = (swz >> 5) * 256;
  const int NT = CC / 64;                     // 32 K-tiles

  const int sr0 = w * 8 + (l >> 3);
  const int skg = l & 7;
  const int fr = l & 15;
  const int fkg = l >> 4;

#define STAGE_AW(tile) do {                                                    \
    const int b_ = (tile) % 3;                                                 \
    const int r0_ = sr0;                                                       \
    const int r1_ = 64 + sr0;                                                  \
    GLD16(A + (size_t)(m0 + r0_) * 2048 + (tile) * 64                          \
              + ((skg ^ (r0_ & 7)) << 3),                                      \
          ldsA[b_] + (w * 8) * 64);                                            \
    GLD16(A + (size_t)(m0 + r1_) * 2048 + (tile) * 64                          \
              + ((skg ^ (r1_ & 7)) << 3),                                      \
          ldsA[b_] + (64 + w * 8) * 64);                                       \
  } while (0)

#define STAGE_BW(tile, half) do {                                              \
    const int b_ = (tile) % 3;                                                 \
    const int r0_ = sr0;                                                       \
    const int r1_ = 64 + sr0;                                                  \
    GLD16(Bm + (size_t)(n0 + (half) * 128 + r0_) * 2048 + (tile) * 64          \
              + ((skg ^ (r0_ & 7)) << 3),                                      \
          ldsB[b_] + ((half) * 128 + w * 8) * 64);                             \
    GLD16(Bm + (size_t)(n0 + (half) * 128 + r1_) * 2048 + (tile) * 64          \
              + ((skg ^ (r1_ & 7)) << 3),                                      \
          ldsB[b_] + ((half) * 128 + 64 + w * 8) * 64);                        \
  } while (0)

#define LDA_FRAGW(dst, ab, mf, ks) do {                                        \
    const int row_ = wm * 64 + (mf) * 16 + fr;                                 \
    const int kg_ = (ks) * 4 + fkg;                                            \
    dst = *(const bf16x8*)&ldsA[ab][row_ * 64 + ((kg_ ^ (row_ & 7)) << 3)];    \
  } while (0)
#define LDB_FRAGW(dst, bb, nf, ks) do {                                        \
    const int row_ = wn * 64 + (nf) * 16 + fr;                                 \
    const int kg_ = (ks) * 4 + fkg;                                            \
    dst = *(const bf16x8*)&ldsB[bb][row_ * 64 + ((kg_ ^ (row_ & 7)) << 3)];    \
  } while (0)

  f32x4 acc[4][4] = {};

  // prologue: tiles 0 and 1 staged (12 loads).
  STAGE_BW(0, 0); STAGE_BW(0, 1); STAGE_AW(0);
  STAGE_BW(1, 0); STAGE_BW(1, 1); STAGE_AW(1);

  for (int t = 0; t < NT; ++t) {
    const int buf = t % 3;
    bf16x8 bfr[4][2];
    bf16x8 af[4][2];

    if (t == NT - 1) asm volatile("s_waitcnt vmcnt(0)" ::: "memory");
    else             asm volatile("s_waitcnt vmcnt(6)" ::: "memory");
    __builtin_amdgcn_s_barrier();

#pragma unroll
    for (int nf = 0; nf < 4; ++nf)
#pragma unroll
      for (int ks = 0; ks < 2; ++ks) LDB_FRAGW(bfr[nf][ks], buf, nf, ks);
#pragma unroll
    for (int mf = 0; mf < 4; ++mf)
#pragma unroll
      for (int ks = 0; ks < 2; ++ks) LDA_FRAGW(af[mf][ks], buf, mf, ks);

    if (t + 2 < NT) { STAGE_BW(t + 2, 0); STAGE_BW(t + 2, 1); STAGE_AW(t + 2); }

    __builtin_amdgcn_s_setprio(1);
#pragma unroll
    for (int mf = 0; mf < 4; ++mf)
#pragma unroll
      for (int nf = 0; nf < 4; ++nf)
#pragma unroll
        for (int ks = 0; ks < 2; ++ks)
          acc[mf][nf] = __builtin_amdgcn_mfma_f32_16x16x32_bf16(
              af[mf][ks], bfr[nf][ks], acc[mf][nf], 0, 0, 0);
    __builtin_amdgcn_s_setprio(0);
  }

  // epilogue: per-wave 64x68 f32 tile in LDS -> float4 stores
  __syncthreads();
  float* ep = (float*)smem + (size_t)w * (64 * 68);
  const int crow = (l >> 4) * 4;
#pragma unroll
  for (int mf = 0; mf < 4; ++mf)
#pragma unroll
    for (int nf = 0; nf < 4; ++nf)
#pragma unroll
      for (int r = 0; r < 4; ++r)
        ep[(mf * 16 + crow + r) * 68 + nf * 16 + fr] = acc[mf][nf][r];
#pragma unroll
  for (int it = 0; it < 16; ++it) {
    const int row = it * 4 + (l >> 4);
    const int c4 = (l & 15) * 4;
    const float4 v4 = *(const float4*)&ep[row * 68 + c4];
    *(float4*)(Cm + (size_t)(m0 + wm * 64 + row) * 2048 + n0 + wn * 64 + c4) = v4;
  }
#undef STAGE_AW
#undef STAGE_BW
#undef LDA_FRAGW
#undef LDB_FRAGW
}

// ---------------------------------------------------------------------------
// fused causal dwconv(K=4)+silu + (k,v) transpose.
// grid (TT/64, CC/64, 3*BB): which = z/BB (0:q 1:k 2:v), b = z%BB.
// ---------------------------------------------------------------------------
__global__ __launch_bounds__(256)
void conv_tr(const __bf16* __restrict__ u_q, const __bf16* __restrict__ u_k,
             const __bf16* __restrict__ u_v, const float* __restrict__ wq,
             const float* __restrict__ wk, const float* __restrict__ wv,
             __bf16* __restrict__ qbf, __bf16* __restrict__ kbf,
             __bf16* __restrict__ kT, __bf16* __restrict__ vT, float qscale)
{
  const int t0 = blockIdx.x * 64, c0 = blockIdx.y * 64;
  const int which = blockIdx.z / BB, b = blockIdx.z % BB;
  const __bf16* u = which == 0 ? u_q : which == 1 ? u_k : u_v;
  const float* wc = which == 0 ? wq : which == 1 ? wk : wv;
  const float scale = which == 0 ? qscale : 1.f;
  const int tid = threadIdx.x;
  __shared__ __attribute__((aligned(16))) __bf16 tile[64][72];

#pragma unroll
  for (int it = 0; it < 2; ++it) {
    const int idx = tid + it * 256;
    const int tl = idx >> 3, g = idx & 7;
    const int t = t0 + tl;
    const int c8 = c0 + g * 8;
    const size_t base = ((size_t)(b * TT + t)) * CC + c8;
    const bf16x8 z = {};
    const bf16x8 uu0 = *(const bf16x8*)(u + base);
    const bf16x8 uu1 = (t >= 1) ? *(const bf16x8*)(u + base - CC)     : z;
    const bf16x8 uu2 = (t >= 2) ? *(const bf16x8*)(u + base - 2 * CC) : z;
    const bf16x8 uu3 = (t >= 3) ? *(const bf16x8*)(u + base - 3 * CC) : z;
    bf16x8 o;
#pragma unroll
    for (int jj = 0; jj < 8; ++jj) {
      const float4 wv4 = *(const float4*)(wc + (size_t)(c8 + jj) * 4);
      const float vv = wv4.x * (float)uu3[jj] + wv4.y * (float)uu2[jj]
                     + wv4.z * (float)uu1[jj] + wv4.w * (float)uu0[jj];
      o[jj] = (__bf16)(vv / (1.f + expf(-vv)) * scale);
    }
    if (which == 0) *(bf16x8*)(qbf + base) = o;
    if (which == 1) *(bf16x8*)(kbf + base) = o;
    if (which >= 1) *(bf16x8*)&tile[tl][g * 8] = o;
  }
  if (which >= 1) {
    __syncthreads();
    const int h = c0 >> 7, d0 = c0 & 127;
    const int bh = b * HH + h;
    __bf16* dst = (which == 1) ? kT : vT;
#pragma unroll
    for (int it = 0; it < 2; ++it) {
      const int idx = tid + it * 256;
      const int dl = idx >> 3, g = idx & 7;
      bf16x8 o;
#pragma unroll
      for (int jj = 0; jj < 8; ++jj) o[jj] = tile[g * 8 + jj][dl];
      *(bf16x8*)(dst + ((size_t)(bh * DD + d0 + dl)) * TT + t0 + g * 8) = o;
    }
  }
}

// ---------------------------------------------------------------------------
// Phase A (MFMA): contribT[e][d] = sum_s (w_s k_s[d]) v_s[e];  decay out.
// ---------------------------------------------------------------------------
__global__ __launch_bounds__(256)
void phaseA_mfma(const __bf16* __restrict__ kT, const __bf16* __restrict__ vT,
                 const float* __restrict__ beta, float* __restrict__ contribT,
                 float* __restrict__ decay)
{
  const int c = blockIdx.x, h = blockIdx.y, b = blockIdx.z;
  const int bh = b * HH + h;
  const int tid = threadIdx.x;
  const int w = tid >> 6, lane = tid & 63;
  const int wm = w >> 1, wn = w & 1;

  __shared__ __attribute__((aligned(16))) __bf16 bufVT[128 * 128];
  __shared__ __attribute__((aligned(16))) __bf16 bufKW[128 * 128];
  __shared__ float lc[CHUNK], bsh[CHUNK], wgt[CHUNK];

  {
    const __bf16* vbase = vT + ((size_t)bh * DD) * TT + c * CHUNK;
#pragma unroll
    for (int jj = 0; jj < 8; ++jj) {
      const int row = w * 32 + jj * 4 + (lane >> 4);
      const int g = lane & 15;
      GLD16(vbase + (size_t)row * TT + ((g ^ (row & 7)) << 3),
            bufVT + (w * 32 + jj * 4) * 128);
    }
  }

  if (tid < CHUNK) {
    const float bv = beta[(size_t)(b * TT + c * CHUNK + tid) * HH + h];
    bsh[tid] = bv;
    lc[tid] = log1pf(-bv);
  }
  __syncthreads();
  for (int off = 1; off < CHUNK; off <<= 1) {
    float add = 0.f;
    if (tid < CHUNK && tid >= off) add = lc[tid - off];
    __syncthreads();
    if (tid < CHUNK) lc[tid] += add;
    __syncthreads();
  }
  const float lend = lc[CHUNK - 1];
  if (tid < CHUNK) wgt[tid] = bsh[tid] * expf(lend - lc[tid]);
  if (tid == 0) decay[(size_t)bh * NC + c] = expf(lend);
  __syncthreads();

  {
    const __bf16* kbase = kT + ((size_t)bh * DD) * TT + c * CHUNK;
#pragma unroll
    for (int it = 0; it < 8; ++it) {
      const int idx = tid + it * 256;
      const int d = idx >> 4, g = idx & 15;
      const bf16x8 kv = *(const bf16x8*)(kbase + (size_t)d * TT + g * 8);
      bf16x8 o;
#pragma unroll
      for (int jj = 0; jj < 8; ++jj)
        o[jj] = (__bf16)((float)kv[jj] * wgt[g * 8 + jj]);
      *(bf16x8*)(bufKW + d * 128 + ((g ^ (d & 7)) << 3)) = o;
    }
  }
  asm volatile("s_waitcnt vmcnt(0)" ::: "memory");
  __syncthreads();

  f32x4 acc[4][4] = {};
#pragma unroll
  for (int ks = 0; ks < 4; ++ks) {
    bf16x8 a[4], bq[4];
    const int kg = ks * 4 + (lane >> 4);
#pragma unroll
    for (int f = 0; f < 4; ++f) a[f]  = ldfrag(bufVT, wm * 64 + f * 16 + (lane & 15), kg);
#pragma unroll
    for (int f = 0; f < 4; ++f) bq[f] = ldfrag(bufKW, wn * 64 + f * 16 + (lane & 15), kg);
#pragma unroll
    for (int i = 0; i < 4; ++i)
#pragma unroll
      for (int j = 0; j < 4; ++j)
        acc[i][j] = __builtin_amdgcn_mfma_f32_16x16x32_bf16(a[i], bq[j], acc[i][j], 0, 0, 0);
  }

  float* cp = contribT + ((size_t)(bh * NC + c) << 14);
  const int crow = (lane >> 4) * 4;
#pragma unroll
  for (int i = 0; i < 4; ++i)
#pragma unroll
    for (int j = 0; j < 4; ++j) {
      const int dd = wn * 64 + j * 16 + (lane & 15);
#pragma unroll
      for (int r = 0; r < 4; ++r) {
        const int e = wm * 64 + i * 16 + crow + r;
        cp[(size_t)e * 128 + dd] = acc[i][j][r];
      }
    }
}

// ---------------------------------------------------------------------------
// Phase B: absorbs both state transposes. st0/stOut are (B,H,D,D) [d][e];
// internal pipeline runs in [e][d] space (coalesced contrib/states access).
// ---------------------------------------------------------------------------
__global__ __launch_bounds__(256)
void phaseB_T(const float* __restrict__ st0, const float* __restrict__ contribT,
              const float* __restrict__ decay, __bf16* __restrict__ statesT,
              float* __restrict__ stOut)
{
  const size_t gid = (size_t)blockIdx.x * 256 + threadIdx.x;
  const int bh = (int)(gid >> 14);
  const int ed = (int)(gid & 16383);
  const int e = ed >> 7, d = ed & 127;
  const size_t tidx = ((size_t)bh << 14) + (size_t)d * 128 + e;
  float s = st0[tidx];
  const float* dc = decay + (size_t)bh * NC;
#pragma unroll
  for (int c = 0; c < NC; ++c) {
    const size_t off = ((size_t)(bh * NC + c) << 14) + ed;
    statesT[off] = (__bf16)s;
    s = fmaf(dc[c], s, contribT[off]);
  }
  stOut[tidx] = s;
}

// ---------------------------------------------------------------------------
// Phase C (MFMA) + fused GroupNorm partial stats.
// ---------------------------------------------------------------------------
__global__ __launch_bounds__(256)
void phaseC_mfma(const __bf16* __restrict__ qb, const __bf16* __restrict__ kb,
                 const __bf16* __restrict__ vT, const float* __restrict__ beta,
                 const __bf16* __restrict__ statesT, float* __restrict__ att,
                 float* __restrict__ partials)
{
  const int c = blockIdx.x, h = blockIdx.y, b = blockIdx.z;
  const int bh = b * HH + h;
  const int tid = threadIdx.x;
  const int w = tid >> 6, lane = tid & 63;
  const int wm = w >> 1, wn = w & 1;

  __shared__ __attribute__((aligned(16))) __bf16 bufQ[128 * 128];
  __shared__ __attribute__((aligned(16))) __bf16 bufB[128 * 128];
  __shared__ float lc[CHUNK], bsh[CHUNK];
  __shared__ float s1[256], s2[256];

  {
    const __bf16* qbase = qb + ((size_t)(b * TT + c * CHUNK)) * CC + h * DD;
    const __bf16* kbase = kb + ((size_t)(b * TT + c * CHUNK)) * CC + h * DD;
#pragma unroll
    for (int jj = 0; jj < 8; ++jj) {
      const int row = w * 32 + jj * 4 + (lane >> 4);
      const int g = lane & 15;
      GLD16(qbase + (size_t)row * CC + ((g ^ (row & 7)) << 3),
            bufQ + (w * 32 + jj * 4) * 128);
      GLD16(kbase + (size_t)row * CC + ((g ^ (row & 7)) << 3),
            bufB + (w * 32 + jj * 4) * 128);
    }
  }

  if (tid < CHUNK) {
    const float bv = beta[(size_t)(b * TT + c * CHUNK + tid) * HH + h];
    bsh[tid] = bv;
    lc[tid] = log1pf(-bv);
  }
  __syncthreads();
  for (int off = 1; off < CHUNK; off <<= 1) {
    float add = 0.f;
    if (tid < CHUNK && tid >= off) add = lc[tid - off];
    __syncthreads();
    if (tid < CHUNK) lc[tid] += add;
    __syncthreads();
  }

  asm volatile("s_waitcnt vmcnt(0)" ::: "memory");
  __syncthreads();

  // S = Q K^T
  f32x4 accS[4][4] = {};
#pragma unroll
  for (int ks = 0; ks < 4; ++ks) {
    bf16x8 a[4], bq[4];
    const int kg = ks * 4 + (lane >> 4);
#pragma unroll
    for (int f = 0; f < 4; ++f) a[f]  = ldfrag(bufQ, wm * 64 + f * 16 + (lane & 15), kg);
#pragma unroll
    for (int f = 0; f < 4; ++f) bq[f] = ldfrag(bufB, wn * 64 + f * 16 + (lane & 15), kg);
#pragma unroll
    for (int i = 0; i < 4; ++i)
#pragma unroll
      for (int j = 0; j < 4; ++j)
        accS[i][j] = __builtin_amdgcn_mfma_f32_16x16x32_bf16(a[i], bq[j], accS[i][j], 0, 0, 0);
  }

  __syncthreads();
  {
    const __bf16* sbase = statesT + ((size_t)(bh * NC + c) << 14);
#pragma unroll
    for (int jj = 0; jj < 8; ++jj) {
      const int row = w * 32 + jj * 4 + (lane >> 4);
      const int g = lane & 15;
      GLD16(sbase + (size_t)row * 128 + ((g ^ (row & 7)) << 3),
            bufB + (w * 32 + jj * 4) * 128);
    }
  }
  asm volatile("s_waitcnt vmcnt(0)" ::: "memory");
  __syncthreads();

  // accO = Q S0T, scaled by e^{lc_t}
  f32x4 accO[4][4] = {};
#pragma unroll
  for (int ks = 0; ks < 4; ++ks) {
    bf16x8 a[4], bq[4];
    const int kg = ks * 4 + (lane >> 4);
#pragma unroll
    for (int f = 0; f < 4; ++f) a[f]  = ldfrag(bufQ, wm * 64 + f * 16 + (lane & 15), kg);
#pragma unroll
    for (int f = 0; f < 4; ++f) bq[f] = ldfrag(bufB, wn * 64 + f * 16 + (lane & 15), kg);
#pragma unroll
    for (int i = 0; i < 4; ++i)
#pragma unroll
      for (int j = 0; j < 4; ++j)
        accO[i][j] = __builtin_amdgcn_mfma_f32_16x16x32_bf16(a[i], bq[j], accO[i][j], 0, 0, 0);
  }
  const int crow = (lane >> 4) * 4;
#pragma unroll
  for (int i = 0; i < 4; ++i)
#pragma unroll
    for (int r = 0; r < 4; ++r) {
      const float el = expf(lc[wm * 64 + i * 16 + crow + r]);
#pragma unroll
      for (int j = 0; j < 4; ++j) accO[i][j][r] *= el;
    }

  __syncthreads();
  {
    const __bf16* vbase = vT + ((size_t)bh * DD) * TT + c * CHUNK;
#pragma unroll
    for (int jj = 0; jj < 8; ++jj) {
      const int row = w * 32 + jj * 4 + (lane >> 4);
      const int g = lane & 15;
      GLD16(vbase + (size_t)row * TT + ((g ^ (row & 7)) << 3),
            bufB + (w * 32 + jj * 4) * 128);
    }
  }
  {
    float lcs[4], bss[4];
#pragma unroll
    for (int j = 0; j < 4; ++j) {
      const int s = wn * 64 + j * 16 + (lane & 15);
      lcs[j] = lc[s]; bss[j] = bsh[s];
    }
#pragma unroll
    for (int i = 0; i < 4; ++i)
#pragma unroll
      for (int r = 0; r < 4; ++r) {
        const int t = wm * 64 + i * 16 + crow + r;
        const float lct = lc[t];
#pragma unroll
        for (int j = 0; j < 4; ++j) {
          const int s = wn * 64 + j * 16 + (lane & 15);
          float p = 0.f;
          if (s <= t) p = accS[i][j][r] * bss[j] * expf(lct - lcs[j]);
          bufQ[t * 128 + (((s >> 3) ^ (t & 7)) << 3) + (s & 7)] = (__bf16)p;
        }
      }
  }
  asm volatile("s_waitcnt vmcnt(0)" ::: "memory");
  __syncthreads();

  // accO += P V^T
#pragma unroll
  for (int ks = 0; ks < 4; ++ks) {
    bf16x8 a[4], bq[4];
    const int kg = ks * 4 + (lane >> 4);
#pragma unroll
    for (int f = 0; f < 4; ++f) a[f]  = ldfrag(bufQ, wm * 64 + f * 16 + (lane & 15), kg);
#pragma unroll
    for (int f = 0; f < 4; ++f) bq[f] = ldfrag(bufB, wn * 64 + f * 16 + (lane & 15), kg);
#pragma unroll
    for (int i = 0; i < 4; ++i)
#pragma unroll
      for (int j = 0; j < 4; ++j)
        accO[i][j] = __builtin_amdgcn_mfma_f32_16x16x32_bf16(a[i], bq[j], accO[i][j], 0, 0, 0);
  }

  // epilogue: store att + accumulate GN partial stats
  float lsum = 0.f, lsq = 0.f;
  float* obase = att + ((size_t)(b * TT + c * CHUNK)) * CC + h * DD;
#pragma unroll
  for (int i = 0; i < 4; ++i)
#pragma unroll
    for (int j = 0; j < 4; ++j) {
      const int e = wn * 64 + j * 16 + (lane & 15);
#pragma unroll
      for (int r = 0; r < 4; ++r) {
        const int t = wm * 64 + i * 16 + crow + r;
        const float vv = accO[i][j][r];
        obase[(size_t)t * CC + e] = vv;
        lsum += vv;
        lsq  += vv * vv;
      }
    }
  s1[tid] = lsum; s2[tid] = lsq;
  __syncthreads();
  for (int off = 128; off; off >>= 1) {
    if (tid < off) { s1[tid] += s1[tid + off]; s2[tid] += s2[tid + off]; }
    __syncthreads();
  }
  if (tid == 0) {
    partials[(size_t)(bh * NC + c) * 2]     = s1[0];
    partials[(size_t)(bh * NC + c) * 2 + 1] = s2[0];
  }
}

// ---------------------------------------------------------------------------
// normalize + gate -> bf16; absorbs GN partial combine (8 heads per block).
// ---------------------------------------------------------------------------
__global__ __launch_bounds__(256)
void norm_gate(const float* __restrict__ att, const __bf16* __restrict__ gate,
               const float* __restrict__ partials, __bf16* __restrict__ g)
{
  __shared__ float sm[8], sr[8];
  const int tid = threadIdx.x;
  const size_t gid0 = (size_t)blockIdx.x * 1024;
  const int b = (int)(gid0 >> 22);
  const int h0 = ((int)(gid0 & 2047)) >> 7;     // 0 or 8
  if (tid < 8) {
    const int bh = b * HH + h0 + tid;
    float s = 0.f, q = 0.f;
#pragma unroll
    for (int cc = 0; cc < NC; ++cc) {
      s += partials[(size_t)(bh * NC + cc) * 2];
      q += partials[(size_t)(bh * NC + cc) * 2 + 1];
    }
    const float n = (float)(TT * DD);
    const float mean = s / n;
    sm[tid] = mean;
    sr[tid] = rsqrtf(q / n - mean * mean + GN_EPS);
  }
  __syncthreads();
  const size_t gid = gid0 + (size_t)tid * 4;
  const int hl = (tid * 4) >> 7;                // 0..7
  const float mean = sm[hl], rstd = sr[hl];
  const float4 a = *(const float4*)(att + gid);
  const bf16x4 gt = *(const bf16x4*)(gate + gid);
  bf16x4 o;
  o[0] = (__bf16)((a.x - mean) * rstd * (float)gt[0]);
  o[1] = (__bf16)((a.y - mean) * rstd * (float)gt[1]);
  o[2] = (__bf16)((a.z - mean) * rstd * (float)gt[2]);
  o[3] = (__bf16)((a.w - mean) * rstd * (float)gt[3]);
  *(bf16x4*)(g + gid) = o;
}

// ---------------------------------------------------------------------------
extern "C" void kernel_launch(void* const* d_in, const int* in_sizes, int n_in,
                              void* d_out, int out_size, void* d_ws, size_t ws_size,
                              hipStream_t stream)
{
  const float* x      = (const float*)d_in[0];
  const float* st0    = (const float*)d_in[1];
  const float* Wq     = (const float*)d_in[2];
  const float* Wk     = (const float*)d_in[3];
  const float* Wv     = (const float*)d_in[4];
  const float* Wbeta  = (const float*)d_in[5];
  const float* Wgate  = (const float*)d_in[6];
  const float* Wo     = (const float*)d_in[7];
  const float* wqc    = (const float*)d_in[8];
  const float* wkc    = (const float*)d_in[9];
  const float* wvc    = (const float*)d_in[10];

  float* ws = (float*)d_ws;
  __bf16* qbf  = (__bf16*)(ws + 0);           // 8.4M bf16
  __bf16* kbf  = (__bf16*)(ws + 4194304);     // 8.4M bf16
  __bf16* u_v  = (__bf16*)(ws + 8388608);     // pre-act v; -> statesT after conv
  __bf16* statesT = (__bf16*)(ws + 8388608);  // (phaseB; u_v dead by then)
  __bf16* kT   = (__bf16*)(ws + 12582912);    // -> gbf after phaseC
  __bf16* gbf  = (__bf16*)(ws + 12582912);
  __bf16* vT   = (__bf16*)(ws + 16777216);
  __bf16* xbf  = (__bf16*)(ws + 20971520);    // dead after gemm_big
  float* contribT = ws + 20971520;            // 8.4M f, overlays xbf + Wcat[0:4.2M]
  __bf16* Wcat = (__bf16*)(ws + 25165824);    // 16.8M bf16 (8192x2048), dead after gemm_big
  __bf16* gatebuf = (__bf16*)(ws + 33554432); // 8.4M bf16, alive GEMM -> norm_gate
  float* betab    = ws + 37748736;            // 65536
  float* decay    = ws + 37814272;            // 512
  float* partials = ws + 37814848;            // 1024
  __bf16* Wob  = (__bf16*)(ws + 38864448);    // 4.2M bf16

  float* y_out  = (float*)d_out;
  float* st_out = (float*)d_out + (size_t)BB * TT * EE;
  __bf16* u_q = (__bf16*)d_out;               // bf16 [0, 8388608)
  __bf16* u_k = (__bf16*)d_out + 8388608;     // bf16 [8388608, 16777216)
  float* att = y_out;

  const dim3 blk(256);
  const dim3 gBig(8192 / 256, (BB * TT) / 256);    // 32 x 16 = 512 blocks
  const dim3 gWo(EE / 256, (BB * TT) / 128);       // 8 x 32 = 256 blocks
  const dim3 gConv(TT / 64, CC / 64, 3 * BB);      // 32 x 32 x 6
  const dim3 gScan(NC, HH, BB);
  const float qscale = 0.08838834764831845f;

  // weight conversions
  convert_w<<<dim3(20480), blk, 0, stream>>>(Wq, Wk, Wv, Wgate, Wo, Wcat, Wob);

  // beta (fp32) + xbf emission
  beta_ker<<<dim3((BB * TT) / 4), blk, 0, stream>>>(x, Wbeta, betab, xbf);

  // merged QKV+gate projection (round-8 schedule + XCD swizzle)
  gemm_big<<<gBig, dim3(512), 0, stream>>>(xbf, Wcat, u_q, u_k, u_v, gatebuf);

  // conv/silu + k,v transposes, fused
  conv_tr<<<gConv, blk, 0, stream>>>(u_q, u_k, u_v, wqc, wkc, wvc,
                                     qbf, kbf, kT, vT, qscale);

  // chunked delta scan (MFMA); phaseB absorbs the state transposes
  phaseA_mfma<<<gScan, blk, 0, stream>>>(kT, vT, betab, contribT, decay);
  phaseB_T<<<dim3((BB * HH * DD * DD) / 256), blk, 0, stream>>>(st0, contribT, decay, statesT, st_out);
  phaseC_mfma<<<gScan, blk, 0, stream>>>(qbf, kbf, vT, betab, statesT, att, partials);

  // groupnorm (combine fused) + gate -> bf16
  norm_gate<<<dim3((BB * TT * CC) / 1024), blk, 0, stream>>>(att, gatebuf, partials, gbf);

  // y = g @ Wo^T (1-phase pipelined 128x256 structure + XCD swizzle)
  gemm_wo<<<gWo, dim3(512), 0, stream>>>(gbf, Wob, y_out);
}

// Round 12
// 328.807 us; speedup vs baseline: 1.0215x; 1.0183x over previous
//
#include <hip/hip_runtime.h>
#include <hip/hip_bf16.h>
#include <math.h>

#define BB 2
#define TT 2048
#define EE 2048
#define HH 16
#define DD 128
#define CC 2048
#define KCONV 4
#define CHUNK 128
#define NC 16          // TT / CHUNK
#define GN_EPS 1e-5f

typedef __bf16 bf16x8 __attribute__((ext_vector_type(8)));
typedef __bf16 bf16x4 __attribute__((ext_vector_type(4)));
typedef float  f32x4  __attribute__((ext_vector_type(4)));

#define GLD16(gp, lp)                                                          \
  __builtin_amdgcn_global_load_lds(                                            \
      (const __attribute__((address_space(1))) void*)(gp),                     \
      (__attribute__((address_space(3))) void*)(lp), 16, 0, 0)

// swizzled fragment load: row-major [128][128] bf16 tile, 16B-group XOR swizzle
__device__ __forceinline__ bf16x8 ldfrag(const __bf16* buf, int row, int kg)
{
  return *(const bf16x8*)(buf + row * 128 + ((kg ^ (row & 7)) << 3));
}

// ---------------------------------------------------------------------------
// f32 -> bf16 conversion for Wq|Wk|Wv|Wgate (into Wcat) and Wo.
// ---------------------------------------------------------------------------
__global__ __launch_bounds__(256)
void convert_w(const float* __restrict__ Wq, const float* __restrict__ Wk,
               const float* __restrict__ Wv, const float* __restrict__ Wg,
               const float* __restrict__ Wo, __bf16* __restrict__ Wcat,
               __bf16* __restrict__ Wob)
{
  const int i = (blockIdx.x * 256 + threadIdx.x) * 4;
  const int WN = 4194304;
  const float* src;
  __bf16* dst;
  int off;
  if (i < 4 * WN) {
    const int seg = i >> 22;
    src = seg == 0 ? Wq : seg == 1 ? Wk : seg == 2 ? Wv : Wg;
    dst = Wcat + ((size_t)seg << 22);
    off = i & (WN - 1);
  } else { src = Wo; dst = Wob; off = i - 4 * WN; }
  const float4 v = *(const float4*)(src + off);
  bf16x4 o;
  o[0] = (__bf16)v.x; o[1] = (__bf16)v.y; o[2] = (__bf16)v.z; o[3] = (__bf16)v.w;
  *(bf16x4*)(dst + off) = o;
}

// ---------------------------------------------------------------------------
// beta = sigmoid(x @ Wbeta^T)  AND emits xbf (x rows are read here anyway).
// ---------------------------------------------------------------------------
__global__ __launch_bounds__(256)
void beta_ker(const float* __restrict__ x, const float* __restrict__ Wb,
              float* __restrict__ betab, __bf16* __restrict__ xbf)
{
  __shared__ float wsb[16 * 1024];   // 64 KB
  const int tid = threadIdx.x;
  const int w = tid >> 6, lane = tid & 63;
  const int row = blockIdx.x * 4 + w;           // < B*T = 4096
  const float* xrow = x + (size_t)row * EE;
  __bf16* xbrow = xbf + (size_t)row * EE;

  float acc[16] = {};
#pragma unroll
  for (int kt = 0; kt < 2; ++kt) {
    __syncthreads();
#pragma unroll
    for (int it = 0; it < 16; ++it) {
      const int i = tid + it * 256;
      const int h = i >> 8, kq = i & 255;
      *(float4*)&wsb[h * 1024 + kq * 4] =
          *(const float4*)(Wb + (size_t)h * EE + kt * 1024 + kq * 4);
    }
    __syncthreads();
#pragma unroll
    for (int j = 0; j < 4; ++j) {
      const int kof = lane * 4 + j * 256;
      const float4 xv = *(const float4*)(xrow + kt * 1024 + kof);
      bf16x4 xb;
      xb[0] = (__bf16)xv.x; xb[1] = (__bf16)xv.y;
      xb[2] = (__bf16)xv.z; xb[3] = (__bf16)xv.w;
      *(bf16x4*)(xbrow + kt * 1024 + kof) = xb;
#pragma unroll
      for (int h = 0; h < 16; ++h) {
        const float4 wv = *(const float4*)&wsb[h * 1024 + kof];
        acc[h] += xv.x * wv.x + xv.y * wv.y + xv.z * wv.z + xv.w * wv.w;
      }
    }
  }
#pragma unroll
  for (int h = 0; h < 16; ++h) {
#pragma unroll
    for (int off = 32; off; off >>= 1)
      acc[h] += __shfl_xor(acc[h], off, 64);
  }
#pragma unroll
  for (int h = 0; h < 16; ++h)
    if (lane == h)
      betab[(size_t)row * HH + h] = 1.f / (1.f + expf(-acc[h]));
}

// ---------------------------------------------------------------------------
// 256x256 deep-pipelined bf16 GEMM (QKV+gate merged), K=2048, BK=64.
// Round-8 proven schedule (no XCD swizzle). ONE barrier per phase.
// ---------------------------------------------------------------------------
__global__ __launch_bounds__(512)
void gemm_big(const __bf16* __restrict__ A, const __bf16* __restrict__ Bm,
              __bf16* __restrict__ o0, __bf16* __restrict__ o1,
              __bf16* __restrict__ o2, __bf16* __restrict__ o3)
{
  __shared__ __attribute__((aligned(16))) unsigned char smem[163840];
  __bf16 (*ldsA)[256 * 64] = (__bf16(*)[256 * 64])smem;             // 3 x 32KB
  __bf16 (*ldsB)[256 * 64] = (__bf16(*)[256 * 64])(smem + 98304);   // 2 x 32KB

  const int tid = threadIdx.x;
  const int w = tid >> 6, l = tid & 63;
  const int wm = w >> 2, wn = w & 3;          // 2 x 4 wave grid
  const int m0 = blockIdx.y * 256, n0 = blockIdx.x * 256;
  const int NT = EE / 64;                     // 32 K-tiles

  const int sr0 = w * 8 + (l >> 3);           // staging dest row, 0..63
  const int skg = l & 7;                      // dest 16B chunk in 128B row
  const int fr = l & 15;
  const int fkg = l >> 4;                     // 0..3

#define STAGE_A(tile, half) do {                                               \
    const int b_ = (tile) % 3;                                                 \
    const int r0_ = sr0;                                                       \
    const int r1_ = 64 + sr0;                                                  \
    GLD16(A + (size_t)(m0 + (half) * 128 + r0_) * 2048 + (tile) * 64           \
              + ((skg ^ (r0_ & 7)) << 3),                                      \
          ldsA[b_] + ((half) * 128 + w * 8) * 64);                             \
    GLD16(A + (size_t)(m0 + (half) * 128 + r1_) * 2048 + (tile) * 64           \
              + ((skg ^ (r1_ & 7)) << 3),                                      \
          ldsA[b_] + ((half) * 128 + 64 + w * 8) * 64);                        \
  } while (0)

#define STAGE_B(tile, half) do {                                               \
    const int b_ = (tile) & 1;                                                 \
    const int r0_ = sr0;                                                       \
    const int r1_ = 64 + sr0;                                                  \
    GLD16(Bm + (size_t)(n0 + (half) * 128 + r0_) * 2048 + (tile) * 64          \
              + ((skg ^ (r0_ & 7)) << 3),                                      \
          ldsB[b_] + ((half) * 128 + w * 8) * 64);                             \
    GLD16(Bm + (size_t)(n0 + (half) * 128 + r1_) * 2048 + (tile) * 64          \
              + ((skg ^ (r1_ & 7)) << 3),                                      \
          ldsB[b_] + ((half) * 128 + 64 + w * 8) * 64);                        \
  } while (0)

#define LDA_FRAG(dst, ab, q, mf, ks) do {                                      \
    const int row_ = wm * 128 + (q) * 32 + (mf) * 16 + fr;                     \
    const int kg_ = (ks) * 4 + fkg;                                            \
    dst = *(const bf16x8*)&ldsA[ab][row_ * 64 + ((kg_ ^ (row_ & 7)) << 3)];    \
  } while (0)
#define LDB_FRAG(dst, bb, nf, ks) do {                                         \
    const int row_ = wn * 64 + (nf) * 16 + fr;                                 \
    const int kg_ = (ks) * 4 + fkg;                                            \
    dst = *(const bf16x8*)&ldsB[bb][row_ * 64 + ((kg_ ^ (row_ & 7)) << 3)];    \
  } while (0)

  f32x4 acc[8][4] = {};

  // prologue: 14 loads; tile 0 resident after vmcnt(6)+barrier.
  STAGE_A(0, 0); STAGE_A(0, 1); STAGE_B(0, 0); STAGE_B(0, 1);
  STAGE_A(1, 0); STAGE_A(1, 1); STAGE_B(1, 0);
  asm volatile("s_waitcnt vmcnt(6)" ::: "memory");
  __builtin_amdgcn_s_barrier();

  for (int t = 0; t < NT; ++t) {
    const int abuf = t % 3;
    const int bbuf = t & 1;
    bf16x8 bfr[4][2];

    // ---- phase q0: all B frags + A quadrant 0; stage B(t+1,1)
    {
      bf16x8 af[2][2];
#pragma unroll
      for (int nf = 0; nf < 4; ++nf)
#pragma unroll
        for (int ks = 0; ks < 2; ++ks) LDB_FRAG(bfr[nf][ks], bbuf, nf, ks);
#pragma unroll
      for (int mf = 0; mf < 2; ++mf)
#pragma unroll
        for (int ks = 0; ks < 2; ++ks) LDA_FRAG(af[mf][ks], abuf, 0, mf, ks);
      if (t + 1 < NT) STAGE_B(t + 1, 1);
      __builtin_amdgcn_s_barrier();
      __builtin_amdgcn_s_setprio(1);
#pragma unroll
      for (int mf = 0; mf < 2; ++mf)
#pragma unroll
        for (int nf = 0; nf < 4; ++nf)
#pragma unroll
          for (int ks = 0; ks < 2; ++ks)
            acc[mf][nf] = __builtin_amdgcn_mfma_f32_16x16x32_bf16(
                af[mf][ks], bfr[nf][ks], acc[mf][nf], 0, 0, 0);
      __builtin_amdgcn_s_setprio(0);
    }

    // ---- phases q1..q3 (one barrier each)
#pragma unroll
    for (int q = 1; q < 4; ++q) {
      bf16x8 af[2][2];
#pragma unroll
      for (int mf = 0; mf < 2; ++mf)
#pragma unroll
        for (int ks = 0; ks < 2; ++ks) LDA_FRAG(af[mf][ks], abuf, q, mf, ks);
      if (q == 1) {
        if (t + 2 < NT) STAGE_A(t + 2, 0);
      } else if (q == 2) {
        if (t + 2 < NT) STAGE_A(t + 2, 1);
      } else {
        if (t + 2 < NT) STAGE_B(t + 2, 0);
        if (t == NT - 2)     asm volatile("s_waitcnt vmcnt(0)" ::: "memory");
        else if (t < NT - 2) asm volatile("s_waitcnt vmcnt(6)" ::: "memory");
      }
      __builtin_amdgcn_s_barrier();
      __builtin_amdgcn_s_setprio(1);
#pragma unroll
      for (int mf = 0; mf < 2; ++mf)
#pragma unroll
        for (int nf = 0; nf < 4; ++nf)
#pragma unroll
          for (int ks = 0; ks < 2; ++ks)
            acc[2 * q + mf][nf] = __builtin_amdgcn_mfma_f32_16x16x32_bf16(
                af[mf][ks], bfr[nf][ks], acc[2 * q + mf][nf], 0, 0, 0);
      __builtin_amdgcn_s_setprio(0);
    }
  }

  // epilogue through LDS: per-wave 128x72 padded tile, coalesced bf16x8 stores
  __syncthreads();
  const int proj = n0 >> 11;
  const int nb = n0 & 2047;
  __bf16* outp = proj == 0 ? o0 : proj == 1 ? o1 : proj == 2 ? o2 : o3;
  __bf16* ep = (__bf16*)smem + (size_t)w * 9216;
  const int crow = (l >> 4) * 4;
#pragma unroll
  for (int mf2 = 0; mf2 < 8; ++mf2)
#pragma unroll
    for (int nf = 0; nf < 4; ++nf)
#pragma unroll
      for (int r = 0; r < 4; ++r) {
        const int row = mf2 * 16 + crow + r;
        float vv = acc[mf2][nf][r];
        if (proj == 3) vv = 1.f / (1.f + expf(-vv));
        ep[row * 72 + nf * 16 + fr] = (__bf16)vv;
      }
#pragma unroll
  for (int it = 0; it < 16; ++it) {
    const int row = it * 8 + (l >> 3);
    const int c8 = (l & 7) * 8;
    const bf16x8 v8 = *(const bf16x8*)&ep[row * 72 + c8];
    *(bf16x8*)(outp + (size_t)(m0 + wm * 128 + row) * 2048 + nb + wn * 64 + c8) = v8;
  }
#undef STAGE_A
#undef STAGE_B
#undef LDA_FRAG
#undef LDB_FRAG
}

// ---------------------------------------------------------------------------
// Wo GEMM, pipelined: BM=128 x BN=256, 256 blocks (1/CU), no swizzle.
// ONE phase per K-tile: vmcnt -> barrier -> reads -> stages(t+2) -> 32 MFMA.
// ---------------------------------------------------------------------------
__global__ __launch_bounds__(512)
void gemm_wo(const __bf16* __restrict__ A, const __bf16* __restrict__ Bm,
             float* __restrict__ Cm)
{
  __shared__ __attribute__((aligned(16))) unsigned char smem[147456];
  __bf16 (*ldsA)[128 * 64] = (__bf16(*)[128 * 64])smem;              // 3 x 16KB
  __bf16 (*ldsB)[256 * 64] = (__bf16(*)[256 * 64])(smem + 49152);    // 3 x 32KB

  const int tid = threadIdx.x;
  const int w = tid >> 6, l = tid & 63;
  const int wm = w >> 2, wn = w & 3;
  const int m0 = blockIdx.y * 128, n0 = blockIdx.x * 256;
  const int NT = CC / 64;                     // 32 K-tiles

  const int sr0 = w * 8 + (l >> 3);
  const int skg = l & 7;
  const int fr = l & 15;
  const int fkg = l >> 4;

#define STAGE_AW(tile) do {                                                    \
    const int b_ = (tile) % 3;                                                 \
    const int r0_ = sr0;                                                       \
    const int r1_ = 64 + sr0;                                                  \
    GLD16(A + (size_t)(m0 + r0_) * 2048 + (tile) * 64                          \
              + ((skg ^ (r0_ & 7)) << 3),                                      \
          ldsA[b_] + (w * 8) * 64);                                            \
    GLD16(A + (size_t)(m0 + r1_) * 2048 + (tile) * 64                          \
              + ((skg ^ (r1_ & 7)) << 3),                                      \
          ldsA[b_] + (64 + w * 8) * 64);                                       \
  } while (0)

#define STAGE_BW(tile, half) do {                                              \
    const int b_ = (tile) % 3;                                                 \
    const int r0_ = sr0;                                                       \
    const int r1_ = 64 + sr0;                                                  \
    GLD16(Bm + (size_t)(n0 + (half) * 128 + r0_) * 2048 + (tile) * 64          \
              + ((skg ^ (r0_ & 7)) << 3),                                      \
          ldsB[b_] + ((half) * 128 + w * 8) * 64);                             \
    GLD16(Bm + (size_t)(n0 + (half) * 128 + r1_) * 2048 + (tile) * 64          \
              + ((skg ^ (r1_ & 7)) << 3),                                      \
          ldsB[b_] + ((half) * 128 + 64 + w * 8) * 64);                        \
  } while (0)

#define LDA_FRAGW(dst, ab, mf, ks) do {                                        \
    const int row_ = wm * 64 + (mf) * 16 + fr;                                 \
    const int kg_ = (ks) * 4 + fkg;                                            \
    dst = *(const bf16x8*)&ldsA[ab][row_ * 64 + ((kg_ ^ (row_ & 7)) << 3)];    \
  } while (0)
#define LDB_FRAGW(dst, bb, nf, ks) do {                                        \
    const int row_ = wn * 64 + (nf) * 16 + fr;                                 \
    const int kg_ = (ks) * 4 + fkg;                                            \
    dst = *(const bf16x8*)&ldsB[bb][row_ * 64 + ((kg_ ^ (row_ & 7)) << 3)];    \
  } while (0)

  f32x4 acc[4][4] = {};

  // prologue: tiles 0 and 1 staged (12 loads).
  STAGE_BW(0, 0); STAGE_BW(0, 1); STAGE_AW(0);
  STAGE_BW(1, 0); STAGE_BW(1, 1); STAGE_AW(1);

  for (int t = 0; t < NT; ++t) {
    const int buf = t % 3;
    bf16x8 bfr[4][2];
    bf16x8 af[4][2];

    if (t == NT - 1) asm volatile("s_waitcnt vmcnt(0)" ::: "memory");
    else             asm volatile("s_waitcnt vmcnt(6)" ::: "memory");
    __builtin_amdgcn_s_barrier();

#pragma unroll
    for (int nf = 0; nf < 4; ++nf)
#pragma unroll
      for (int ks = 0; ks < 2; ++ks) LDB_FRAGW(bfr[nf][ks], buf, nf, ks);
#pragma unroll
    for (int mf = 0; mf < 4; ++mf)
#pragma unroll
      for (int ks = 0; ks < 2; ++ks) LDA_FRAGW(af[mf][ks], buf, mf, ks);

    if (t + 2 < NT) { STAGE_BW(t + 2, 0); STAGE_BW(t + 2, 1); STAGE_AW(t + 2); }

    __builtin_amdgcn_s_setprio(1);
#pragma unroll
    for (int mf = 0; mf < 4; ++mf)
#pragma unroll
      for (int nf = 0; nf < 4; ++nf)
#pragma unroll
        for (int ks = 0; ks < 2; ++ks)
          acc[mf][nf] = __builtin_amdgcn_mfma_f32_16x16x32_bf16(
              af[mf][ks], bfr[nf][ks], acc[mf][nf], 0, 0, 0);
    __builtin_amdgcn_s_setprio(0);
  }

  // epilogue: per-wave 64x68 f32 tile in LDS -> float4 stores
  __syncthreads();
  float* ep = (float*)smem + (size_t)w * (64 * 68);
  const int crow = (l >> 4) * 4;
#pragma unroll
  for (int mf = 0; mf < 4; ++mf)
#pragma unroll
    for (int nf = 0; nf < 4; ++nf)
#pragma unroll
      for (int r = 0; r < 4; ++r)
        ep[(mf * 16 + crow + r) * 68 + nf * 16 + fr] = acc[mf][nf][r];
#pragma unroll
  for (int it = 0; it < 16; ++it) {
    const int row = it * 4 + (l >> 4);
    const int c4 = (l & 15) * 4;
    const float4 v4 = *(const float4*)&ep[row * 68 + c4];
    *(float4*)(Cm + (size_t)(m0 + wm * 64 + row) * 2048 + n0 + wn * 64 + c4) = v4;
  }
#undef STAGE_AW
#undef STAGE_BW
#undef LDA_FRAGW
#undef LDB_FRAGW
}

// ---------------------------------------------------------------------------
// fused causal dwconv(K=4)+silu + (k,v) transpose.
// ---------------------------------------------------------------------------
__global__ __launch_bounds__(256)
void conv_tr(const __bf16* __restrict__ u_q, const __bf16* __restrict__ u_k,
             const __bf16* __restrict__ u_v, const float* __restrict__ wq,
             const float* __restrict__ wk, const float* __restrict__ wv,
             __bf16* __restrict__ qbf, __bf16* __restrict__ kbf,
             __bf16* __restrict__ kT, __bf16* __restrict__ vT, float qscale)
{
  const int t0 = blockIdx.x * 64, c0 = blockIdx.y * 64;
  const int which = blockIdx.z / BB, b = blockIdx.z % BB;
  const __bf16* u = which == 0 ? u_q : which == 1 ? u_k : u_v;
  const float* wc = which == 0 ? wq : which == 1 ? wk : wv;
  const float scale = which == 0 ? qscale : 1.f;
  const int tid = threadIdx.x;
  __shared__ __attribute__((aligned(16))) __bf16 tile[64][72];

#pragma unroll
  for (int it = 0; it < 2; ++it) {
    const int idx = tid + it * 256;
    const int tl = idx >> 3, g = idx & 7;
    const int t = t0 + tl;
    const int c8 = c0 + g * 8;
    const size_t base = ((size_t)(b * TT + t)) * CC + c8;
    const bf16x8 z = {};
    const bf16x8 uu0 = *(const bf16x8*)(u + base);
    const bf16x8 uu1 = (t >= 1) ? *(const bf16x8*)(u + base - CC)     : z;
    const bf16x8 uu2 = (t >= 2) ? *(const bf16x8*)(u + base - 2 * CC) : z;
    const bf16x8 uu3 = (t >= 3) ? *(const bf16x8*)(u + base - 3 * CC) : z;
    bf16x8 o;
#pragma unroll
    for (int jj = 0; jj < 8; ++jj) {
      const float4 wv4 = *(const float4*)(wc + (size_t)(c8 + jj) * 4);
      const float vv = wv4.x * (float)uu3[jj] + wv4.y * (float)uu2[jj]
                     + wv4.z * (float)uu1[jj] + wv4.w * (float)uu0[jj];
      o[jj] = (__bf16)(vv / (1.f + expf(-vv)) * scale);
    }
    if (which == 0) *(bf16x8*)(qbf + base) = o;
    if (which == 1) *(bf16x8*)(kbf + base) = o;
    if (which >= 1) *(bf16x8*)&tile[tl][g * 8] = o;
  }
  if (which >= 1) {
    __syncthreads();
    const int h = c0 >> 7, d0 = c0 & 127;
    const int bh = b * HH + h;
    __bf16* dst = (which == 1) ? kT : vT;
#pragma unroll
    for (int it = 0; it < 2; ++it) {
      const int idx = tid + it * 256;
      const int dl = idx >> 3, g = idx & 7;
      bf16x8 o;
#pragma unroll
      for (int jj = 0; jj < 8; ++jj) o[jj] = tile[g * 8 + jj][dl];
      *(bf16x8*)(dst + ((size_t)(bh * DD + d0 + dl)) * TT + t0 + g * 8) = o;
    }
  }
}

// ---------------------------------------------------------------------------
// Phase A (MFMA): contribT[e][d] = sum_s (w_s k_s[d]) v_s[e];  decay out.
// ---------------------------------------------------------------------------
__global__ __launch_bounds__(256)
void phaseA_mfma(const __bf16* __restrict__ kT, const __bf16* __restrict__ vT,
                 const float* __restrict__ beta, float* __restrict__ contribT,
                 float* __restrict__ decay)
{
  const int c = blockIdx.x, h = blockIdx.y, b = blockIdx.z;
  const int bh = b * HH + h;
  const int tid = threadIdx.x;
  const int w = tid >> 6, lane = tid & 63;
  const int wm = w >> 1, wn = w & 1;

  __shared__ __attribute__((aligned(16))) __bf16 bufVT[128 * 128];
  __shared__ __attribute__((aligned(16))) __bf16 bufKW[128 * 128];
  __shared__ float lc[CHUNK], bsh[CHUNK], wgt[CHUNK];

  {
    const __bf16* vbase = vT + ((size_t)bh * DD) * TT + c * CHUNK;
#pragma unroll
    for (int jj = 0; jj < 8; ++jj) {
      const int row = w * 32 + jj * 4 + (lane >> 4);
      const int g = lane & 15;
      GLD16(vbase + (size_t)row * TT + ((g ^ (row & 7)) << 3),
            bufVT + (w * 32 + jj * 4) * 128);
    }
  }

  if (tid < CHUNK) {
    const float bv = beta[(size_t)(b * TT + c * CHUNK + tid) * HH + h];
    bsh[tid] = bv;
    lc[tid] = log1pf(-bv);
  }
  __syncthreads();
  for (int off = 1; off < CHUNK; off <<= 1) {
    float add = 0.f;
    if (tid < CHUNK && tid >= off) add = lc[tid - off];
    __syncthreads();
    if (tid < CHUNK) lc[tid] += add;
    __syncthreads();
  }
  const float lend = lc[CHUNK - 1];
  if (tid < CHUNK) wgt[tid] = bsh[tid] * expf(lend - lc[tid]);
  if (tid == 0) decay[(size_t)bh * NC + c] = expf(lend);
  __syncthreads();

  {
    const __bf16* kbase = kT + ((size_t)bh * DD) * TT + c * CHUNK;
#pragma unroll
    for (int it = 0; it < 8; ++it) {
      const int idx = tid + it * 256;
      const int d = idx >> 4, g = idx & 15;
      const bf16x8 kv = *(const bf16x8*)(kbase + (size_t)d * TT + g * 8);
      bf16x8 o;
#pragma unroll
      for (int jj = 0; jj < 8; ++jj)
        o[jj] = (__bf16)((float)kv[jj] * wgt[g * 8 + jj]);
      *(bf16x8*)(bufKW + d * 128 + ((g ^ (d & 7)) << 3)) = o;
    }
  }
  asm volatile("s_waitcnt vmcnt(0)" ::: "memory");
  __syncthreads();

  f32x4 acc[4][4] = {};
#pragma unroll
  for (int ks = 0; ks < 4; ++ks) {
    bf16x8 a[4], bq[4];
    const int kg = ks * 4 + (lane >> 4);
#pragma unroll
    for (int f = 0; f < 4; ++f) a[f]  = ldfrag(bufVT, wm * 64 + f * 16 + (lane & 15), kg);
#pragma unroll
    for (int f = 0; f < 4; ++f) bq[f] = ldfrag(bufKW, wn * 64 + f * 16 + (lane & 15), kg);
#pragma unroll
    for (int i = 0; i < 4; ++i)
#pragma unroll
      for (int j = 0; j < 4; ++j)
        acc[i][j] = __builtin_amdgcn_mfma_f32_16x16x32_bf16(a[i], bq[j], acc[i][j], 0, 0, 0);
  }

  float* cp = contribT + ((size_t)(bh * NC + c) << 14);
  const int crow = (lane >> 4) * 4;
#pragma unroll
  for (int i = 0; i < 4; ++i)
#pragma unroll
    for (int j = 0; j < 4; ++j) {
      const int dd = wn * 64 + j * 16 + (lane & 15);
#pragma unroll
      for (int r = 0; r < 4; ++r) {
        const int e = wm * 64 + i * 16 + crow + r;
        cp[(size_t)e * 128 + dd] = acc[i][j][r];
      }
    }
}

// ---------------------------------------------------------------------------
// Phase B: absorbs both state transposes.
// ---------------------------------------------------------------------------
__global__ __launch_bounds__(256)
void phaseB_T(const float* __restrict__ st0, const float* __restrict__ contribT,
              const float* __restrict__ decay, __bf16* __restrict__ statesT,
              float* __restrict__ stOut)
{
  const size_t gid = (size_t)blockIdx.x * 256 + threadIdx.x;
  const int bh = (int)(gid >> 14);
  const int ed = (int)(gid & 16383);
  const int e = ed >> 7, d = ed & 127;
  const size_t tidx = ((size_t)bh << 14) + (size_t)d * 128 + e;
  float s = st0[tidx];
  const float* dc = decay + (size_t)bh * NC;
#pragma unroll
  for (int c = 0; c < NC; ++c) {
    const size_t off = ((size_t)(bh * NC + c) << 14) + ed;
    statesT[off] = (__bf16)s;
    s = fmaf(dc[c], s, contribT[off]);
  }
  stOut[tidx] = s;
}

// ---------------------------------------------------------------------------
// Phase C v2 (MFMA) + fused GroupNorm partial stats.
// Q fragments loaded DIRECTLY into registers (row-major 16B/lane).
// bufA: K then P.  bufB: S0T then V.  S0T staged at prologue (hidden under
// beta scan + QK^T); V staged overlapping the P transform.
// ---------------------------------------------------------------------------
__global__ __launch_bounds__(256)
void phaseC_mfma(const __bf16* __restrict__ qb, const __bf16* __restrict__ kb,
                 const __bf16* __restrict__ vT, const float* __restrict__ beta,
                 const __bf16* __restrict__ statesT, float* __restrict__ att,
                 float* __restrict__ partials)
{
  const int c = blockIdx.x, h = blockIdx.y, b = blockIdx.z;
  const int bh = b * HH + h;
  const int tid = threadIdx.x;
  const int w = tid >> 6, lane = tid & 63;
  const int wm = w >> 1, wn = w & 1;

  __shared__ __attribute__((aligned(16))) __bf16 bufA[128 * 128];  // K -> P
  __shared__ __attribute__((aligned(16))) __bf16 bufB[128 * 128];  // S0T -> V
  __shared__ float lc[CHUNK], bsh[CHUNK];
  __shared__ float s1[256], s2[256];

  // direct Q fragment loads into registers (A-operand of QK^T and Q*S0T)
  bf16x8 qf[4][4];
  {
    const __bf16* qbase = qb + ((size_t)(b * TT + c * CHUNK + wm * 64 + (lane & 15))) * CC
                        + h * DD + (lane >> 4) * 8;
#pragma unroll
    for (int f = 0; f < 4; ++f)
#pragma unroll
      for (int ks = 0; ks < 4; ++ks)
        qf[f][ks] = *(const bf16x8*)(qbase + (size_t)f * 16 * CC + ks * 32);
  }

  // stage K -> bufA, S0T -> bufB (async; hidden under beta scan)
  {
    const __bf16* kbase = kb + ((size_t)(b * TT + c * CHUNK)) * CC + h * DD;
    const __bf16* sbase = statesT + ((size_t)(bh * NC + c) << 14);
#pragma unroll
    for (int jj = 0; jj < 8; ++jj) {
      const int row = w * 32 + jj * 4 + (lane >> 4);
      const int g = lane & 15;
      GLD16(kbase + (size_t)row * CC + ((g ^ (row & 7)) << 3),
            bufA + (w * 32 + jj * 4) * 128);
      GLD16(sbase + (size_t)row * 128 + ((g ^ (row & 7)) << 3),
            bufB + (w * 32 + jj * 4) * 128);
    }
  }

  if (tid < CHUNK) {
    const float bv = beta[(size_t)(b * TT + c * CHUNK + tid) * HH + h];
    bsh[tid] = bv;
    lc[tid] = log1pf(-bv);
  }
  __syncthreads();
  for (int off = 1; off < CHUNK; off <<= 1) {
    float add = 0.f;
    if (tid < CHUNK && tid >= off) add = lc[tid - off];
    __syncthreads();
    if (tid < CHUNK) lc[tid] += add;
    __syncthreads();
  }

  asm volatile("s_waitcnt vmcnt(0)" ::: "memory");
  __syncthreads();

  // S = Q K^T  (A = qf regs, B = bufA)
  f32x4 accS[4][4] = {};
#pragma unroll
  for (int ks = 0; ks < 4; ++ks) {
    bf16x8 bq[4];
    const int kg = ks * 4 + (lane >> 4);
#pragma unroll
    for (int f = 0; f < 4; ++f) bq[f] = ldfrag(bufA, wn * 64 + f * 16 + (lane & 15), kg);
#pragma unroll
    for (int i = 0; i < 4; ++i)
#pragma unroll
      for (int j = 0; j < 4; ++j)
        accS[i][j] = __builtin_amdgcn_mfma_f32_16x16x32_bf16(qf[i][ks], bq[j], accS[i][j], 0, 0, 0);
  }

  // accO = Q S0T  (A = qf regs, B = bufB) — no barrier needed (disjoint bufs)
  f32x4 accO[4][4] = {};
#pragma unroll
  for (int ks = 0; ks < 4; ++ks) {
    bf16x8 bq[4];
    const int kg = ks * 4 + (lane >> 4);
#pragma unroll
    for (int f = 0; f < 4; ++f) bq[f] = ldfrag(bufB, wn * 64 + f * 16 + (lane & 15), kg);
#pragma unroll
    for (int i = 0; i < 4; ++i)
#pragma unroll
      for (int j = 0; j < 4; ++j)
        accO[i][j] = __builtin_amdgcn_mfma_f32_16x16x32_bf16(qf[i][ks], bq[j], accO[i][j], 0, 0, 0);
  }
  const int crow = (lane >> 4) * 4;
#pragma unroll
  for (int i = 0; i < 4; ++i)
#pragma unroll
    for (int r = 0; r < 4; ++r) {
      const float el = expf(lc[wm * 64 + i * 16 + crow + r]);
#pragma unroll
      for (int j = 0; j < 4; ++j) accO[i][j][r] *= el;
    }

  __syncthreads();   // all bufA (QK^T) and bufB (QS0T) reads complete

  // stage V -> bufB (issued before P VALU work so latency hides under it)
  {
    const __bf16* vbase = vT + ((size_t)bh * DD) * TT + c * CHUNK;
#pragma unroll
    for (int jj = 0; jj < 8; ++jj) {
      const int row = w * 32 + jj * 4 + (lane >> 4);
      const int g = lane & 15;
      GLD16(vbase + (size_t)row * TT + ((g ^ (row & 7)) << 3),
            bufB + (w * 32 + jj * 4) * 128);
    }
  }
  // transform S -> P, write bf16 swizzled into bufA
  {
    float lcs[4], bss[4];
#pragma unroll
    for (int j = 0; j < 4; ++j) {
      const int s = wn * 64 + j * 16 + (lane & 15);
      lcs[j] = lc[s]; bss[j] = bsh[s];
    }
#pragma unroll
    for (int i = 0; i < 4; ++i)
#pragma unroll
      for (int r = 0; r < 4; ++r) {
        const int t = wm * 64 + i * 16 + crow + r;
        const float lct = lc[t];
#pragma unroll
        for (int j = 0; j < 4; ++j) {
          const int s = wn * 64 + j * 16 + (lane & 15);
          float p = 0.f;
          if (s <= t) p = accS[i][j][r] * bss[j] * expf(lct - lcs[j]);
          bufA[t * 128 + (((s >> 3) ^ (t & 7)) << 3) + (s & 7)] = (__bf16)p;
        }
      }
  }
  asm volatile("s_waitcnt vmcnt(0)" ::: "memory");
  __syncthreads();

  // accO += P V^T
#pragma unroll
  for (int ks = 0; ks < 4; ++ks) {
    bf16x8 a[4], bq[4];
    const int kg = ks * 4 + (lane >> 4);
#pragma unroll
    for (int f = 0; f < 4; ++f) a[f]  = ldfrag(bufA, wm * 64 + f * 16 + (lane & 15), kg);
#pragma unroll
    for (int f = 0; f < 4; ++f) bq[f] = ldfrag(bufB, wn * 64 + f * 16 + (lane & 15), kg);
#pragma unroll
    for (int i = 0; i < 4; ++i)
#pragma unroll
      for (int j = 0; j < 4; ++j)
        accO[i][j] = __builtin_amdgcn_mfma_f32_16x16x32_bf16(a[i], bq[j], accO[i][j], 0, 0, 0);
  }

  // epilogue: store att + accumulate GN partial stats
  float lsum = 0.f, lsq = 0.f;
  float* obase = att + ((size_t)(b * TT + c * CHUNK)) * CC + h * DD;
#pragma unroll
  for (int i = 0; i < 4; ++i)
#pragma unroll
    for (int j = 0; j < 4; ++j) {
      const int e = wn * 64 + j * 16 + (lane & 15);
#pragma unroll
      for (int r = 0; r < 4; ++r) {
        const int t = wm * 64 + i * 16 + crow + r;
        const float vv = accO[i][j][r];
        obase[(size_t)t * CC + e] = vv;
        lsum += vv;
        lsq  += vv * vv;
      }
    }
  s1[tid] = lsum; s2[tid] = lsq;
  __syncthreads();
  for (int off = 128; off; off >>= 1) {
    if (tid < off) { s1[tid] += s1[tid + off]; s2[tid] += s2[tid + off]; }
    __syncthreads();
  }
  if (tid == 0) {
    partials[(size_t)(bh * NC + c) * 2]     = s1[0];
    partials[(size_t)(bh * NC + c) * 2 + 1] = s2[0];
  }
}

// ---------------------------------------------------------------------------
// normalize + gate -> bf16; absorbs GN partial combine (8 heads per block).
// ---------------------------------------------------------------------------
__global__ __launch_bounds__(256)
void norm_gate(const float* __restrict__ att, const __bf16* __restrict__ gate,
               const float* __restrict__ partials, __bf16* __restrict__ g)
{
  __shared__ float sm[8], sr[8];
  const int tid = threadIdx.x;
  const size_t gid0 = (size_t)blockIdx.x * 1024;
  const int b = (int)(gid0 >> 22);
  const int h0 = ((int)(gid0 & 2047)) >> 7;     // 0 or 8
  if (tid < 8) {
    const int bh = b * HH + h0 + tid;
    float s = 0.f, q = 0.f;
#pragma unroll
    for (int cc = 0; cc < NC; ++cc) {
      s += partials[(size_t)(bh * NC + cc) * 2];
      q += partials[(size_t)(bh * NC + cc) * 2 + 1];
    }
    const float n = (float)(TT * DD);
    const float mean = s / n;
    sm[tid] = mean;
    sr[tid] = rsqrtf(q / n - mean * mean + GN_EPS);
  }
  __syncthreads();
  const size_t gid = gid0 + (size_t)tid * 4;
  const int hl = (tid * 4) >> 7;                // 0..7
  const float mean = sm[hl], rstd = sr[hl];
  const float4 a = *(const float4*)(att + gid);
  const bf16x4 gt = *(const bf16x4*)(gate + gid);
  bf16x4 o;
  o[0] = (__bf16)((a.x - mean) * rstd * (float)gt[0]);
  o[1] = (__bf16)((a.y - mean) * rstd * (float)gt[1]);
  o[2] = (__bf16)((a.z - mean) * rstd * (float)gt[2]);
  o[3] = (__bf16)((a.w - mean) * rstd * (float)gt[3]);
  *(bf16x4*)(g + gid) = o;
}

// ---------------------------------------------------------------------------
extern "C" void kernel_launch(void* const* d_in, const int* in_sizes, int n_in,
                              void* d_out, int out_size, void* d_ws, size_t ws_size,
                              hipStream_t stream)
{
  const float* x      = (const float*)d_in[0];
  const float* st0    = (const float*)d_in[1];
  const float* Wq     = (const float*)d_in[2];
  const float* Wk     = (const float*)d_in[3];
  const float* Wv     = (const float*)d_in[4];
  const float* Wbeta  = (const float*)d_in[5];
  const float* Wgate  = (const float*)d_in[6];
  const float* Wo     = (const float*)d_in[7];
  const float* wqc    = (const float*)d_in[8];
  const float* wkc    = (const float*)d_in[9];
  const float* wvc    = (const float*)d_in[10];

  float* ws = (float*)d_ws;
  __bf16* qbf  = (__bf16*)(ws + 0);           // 8.4M bf16
  __bf16* kbf  = (__bf16*)(ws + 4194304);     // 8.4M bf16
  __bf16* u_v  = (__bf16*)(ws + 8388608);     // pre-act v; -> statesT after conv
  __bf16* statesT = (__bf16*)(ws + 8388608);  // (phaseB; u_v dead by then)
  __bf16* kT   = (__bf16*)(ws + 12582912);    // -> gbf after phaseC
  __bf16* gbf  = (__bf16*)(ws + 12582912);
  __bf16* vT   = (__bf16*)(ws + 16777216);
  __bf16* xbf  = (__bf16*)(ws + 20971520);    // dead after gemm_big
  float* contribT = ws + 20971520;            // 8.4M f, overlays xbf + Wcat[0:4.2M]
  __bf16* Wcat = (__bf16*)(ws + 25165824);    // 16.8M bf16 (8192x2048), dead after gemm_big
  __bf16* gatebuf = (__bf16*)(ws + 33554432); // 8.4M bf16, alive GEMM -> norm_gate
  float* betab    = ws + 37748736;            // 65536
  float* decay    = ws + 37814272;            // 512
  float* partials = ws + 37814848;            // 1024
  __bf16* Wob  = (__bf16*)(ws + 38864448);    // 4.2M bf16

  float* y_out  = (float*)d_out;
  float* st_out = (float*)d_out + (size_t)BB * TT * EE;
  __bf16* u_q = (__bf16*)d_out;               // bf16 [0, 8388608)
  __bf16* u_k = (__bf16*)d_out + 8388608;     // bf16 [8388608, 16777216)
  float* att = y_out;

  const dim3 blk(256);
  const dim3 gBig(8192 / 256, (BB * TT) / 256);    // 32 x 16 = 512 blocks
  const dim3 gWo(EE / 256, (BB * TT) / 128);       // 8 x 32 = 256 blocks
  const dim3 gConv(TT / 64, CC / 64, 3 * BB);      // 32 x 32 x 6
  const dim3 gScan(NC, HH, BB);
  const float qscale = 0.08838834764831845f;

  // weight conversions
  convert_w<<<dim3(20480), blk, 0, stream>>>(Wq, Wk, Wv, Wgate, Wo, Wcat, Wob);

  // beta (fp32) + xbf emission
  beta_ker<<<dim3((BB * TT) / 4), blk, 0, stream>>>(x, Wbeta, betab, xbf);

  // merged QKV+gate projection (round-8 schedule, no swizzle)
  gemm_big<<<gBig, dim3(512), 0, stream>>>(xbf, Wcat, u_q, u_k, u_v, gatebuf);

  // conv/silu + k,v transposes, fused
  conv_tr<<<gConv, blk, 0, stream>>>(u_q, u_k, u_v, wqc, wkc, wvc,
                                     qbf, kbf, kT, vT, qscale);

  // chunked delta scan (MFMA); phaseB absorbs the state transposes
  phaseA_mfma<<<gScan, blk, 0, stream>>>(kT, vT, betab, contribT, decay);
  phaseB_T<<<dim3((BB * HH * DD * DD) / 256), blk, 0, stream>>>(st0, contribT, decay, statesT, st_out);
  phaseC_mfma<<<gScan, blk, 0, stream>>>(qbf, kbf, vT, betab, statesT, att, partials);

  // groupnorm (combine fused) + gate -> bf16
  norm_gate<<<dim3((BB * TT * CC) / 1024), blk, 0, stream>>>(att, gatebuf, partials, gbf);

  // y = g @ Wo^T (1-phase pipelined 128x256 structure, no swizzle)
  gemm_wo<<<gWo, dim3(512), 0, stream>>>(gbf, Wob, y_out);
}

// Round 13
// 324.327 us; speedup vs baseline: 1.0356x; 1.0138x over previous
//
#include <hip/hip_runtime.h>
#include <hip/hip_bf16.h>
#include <math.h>

#define BB 2
#define TT 2048
#define EE 2048
#define HH 16
#define DD 128
#define CC 2048
#define KCONV 4
#define CHUNK 128
#define NC 16          // TT / CHUNK
#define GN_EPS 1e-5f

typedef __bf16 bf16x8 __attribute__((ext_vector_type(8)));
typedef __bf16 bf16x4 __attribute__((ext_vector_type(4)));
typedef float  f32x4  __attribute__((ext_vector_type(4)));

#define GLD16(gp, lp)                                                          \
  __builtin_amdgcn_global_load_lds(                                            \
      (const __attribute__((address_space(1))) void*)(gp),                     \
      (__attribute__((address_space(3))) void*)(lp), 16, 0, 0)

// swizzled fragment load: row-major [128][128] bf16 tile, 16B-group XOR swizzle
__device__ __forceinline__ bf16x8 ldfrag(const __bf16* buf, int row, int kg)
{
  return *(const bf16x8*)(buf + row * 128 + ((kg ^ (row & 7)) << 3));
}

// ---------------------------------------------------------------------------
// f32 -> bf16 conversion for Wq|Wk|Wv|Wgate (into Wcat) and Wo.
// ---------------------------------------------------------------------------
__global__ __launch_bounds__(256)
void convert_w(const float* __restrict__ Wq, const float* __restrict__ Wk,
               const float* __restrict__ Wv, const float* __restrict__ Wg,
               const float* __restrict__ Wo, __bf16* __restrict__ Wcat,
               __bf16* __restrict__ Wob)
{
  const int i = (blockIdx.x * 256 + threadIdx.x) * 4;
  const int WN = 4194304;
  const float* src;
  __bf16* dst;
  int off;
  if (i < 4 * WN) {
    const int seg = i >> 22;
    src = seg == 0 ? Wq : seg == 1 ? Wk : seg == 2 ? Wv : Wg;
    dst = Wcat + ((size_t)seg << 22);
    off = i & (WN - 1);
  } else { src = Wo; dst = Wob; off = i - 4 * WN; }
  const float4 v = *(const float4*)(src + off);
  bf16x4 o;
  o[0] = (__bf16)v.x; o[1] = (__bf16)v.y; o[2] = (__bf16)v.z; o[3] = (__bf16)v.w;
  *(bf16x4*)(dst + off) = o;
}

// ---------------------------------------------------------------------------
// beta = sigmoid(x @ Wbeta^T)  AND emits xbf (x rows are read here anyway).
// ---------------------------------------------------------------------------
__global__ __launch_bounds__(256)
void beta_ker(const float* __restrict__ x, const float* __restrict__ Wb,
              float* __restrict__ betab, __bf16* __restrict__ xbf)
{
  __shared__ float wsb[16 * 1024];   // 64 KB
  const int tid = threadIdx.x;
  const int w = tid >> 6, lane = tid & 63;
  const int row = blockIdx.x * 4 + w;           // < B*T = 4096
  const float* xrow = x + (size_t)row * EE;
  __bf16* xbrow = xbf + (size_t)row * EE;

  float acc[16] = {};
#pragma unroll
  for (int kt = 0; kt < 2; ++kt) {
    __syncthreads();
#pragma unroll
    for (int it = 0; it < 16; ++it) {
      const int i = tid + it * 256;
      const int h = i >> 8, kq = i & 255;
      *(float4*)&wsb[h * 1024 + kq * 4] =
          *(const float4*)(Wb + (size_t)h * EE + kt * 1024 + kq * 4);
    }
    __syncthreads();
#pragma unroll
    for (int j = 0; j < 4; ++j) {
      const int kof = lane * 4 + j * 256;
      const float4 xv = *(const float4*)(xrow + kt * 1024 + kof);
      bf16x4 xb;
      xb[0] = (__bf16)xv.x; xb[1] = (__bf16)xv.y;
      xb[2] = (__bf16)xv.z; xb[3] = (__bf16)xv.w;
      *(bf16x4*)(xbrow + kt * 1024 + kof) = xb;
#pragma unroll
      for (int h = 0; h < 16; ++h) {
        const float4 wv = *(const float4*)&wsb[h * 1024 + kof];
        acc[h] += xv.x * wv.x + xv.y * wv.y + xv.z * wv.z + xv.w * wv.w;
      }
    }
  }
#pragma unroll
  for (int h = 0; h < 16; ++h) {
#pragma unroll
    for (int off = 32; off; off >>= 1)
      acc[h] += __shfl_xor(acc[h], off, 64);
  }
#pragma unroll
  for (int h = 0; h < 16; ++h)
    if (lane == h)
      betab[(size_t)row * HH + h] = 1.f / (1.f + expf(-acc[h]));
}

// ---------------------------------------------------------------------------
// 256x256 deep-pipelined bf16 GEMM (QKV+gate merged), K=2048, BK=64.
// Round-8 proven schedule. ONE barrier per phase.
// ---------------------------------------------------------------------------
__global__ __launch_bounds__(512)
void gemm_big(const __bf16* __restrict__ A, const __bf16* __restrict__ Bm,
              __bf16* __restrict__ o0, __bf16* __restrict__ o1,
              __bf16* __restrict__ o2, __bf16* __restrict__ o3)
{
  __shared__ __attribute__((aligned(16))) unsigned char smem[163840];
  __bf16 (*ldsA)[256 * 64] = (__bf16(*)[256 * 64])smem;             // 3 x 32KB
  __bf16 (*ldsB)[256 * 64] = (__bf16(*)[256 * 64])(smem + 98304);   // 2 x 32KB

  const int tid = threadIdx.x;
  const int w = tid >> 6, l = tid & 63;
  const int wm = w >> 2, wn = w & 3;          // 2 x 4 wave grid
  const int m0 = blockIdx.y * 256, n0 = blockIdx.x * 256;
  const int NT = EE / 64;                     // 32 K-tiles

  const int sr0 = w * 8 + (l >> 3);           // staging dest row, 0..63
  const int skg = l & 7;                      // dest 16B chunk in 128B row
  const int fr = l & 15;
  const int fkg = l >> 4;                     // 0..3

#define STAGE_A(tile, half) do {                                               \
    const int b_ = (tile) % 3;                                                 \
    const int r0_ = sr0;                                                       \
    const int r1_ = 64 + sr0;                                                  \
    GLD16(A + (size_t)(m0 + (half) * 128 + r0_) * 2048 + (tile) * 64           \
              + ((skg ^ (r0_ & 7)) << 3),                                      \
          ldsA[b_] + ((half) * 128 + w * 8) * 64);                             \
    GLD16(A + (size_t)(m0 + (half) * 128 + r1_) * 2048 + (tile) * 64           \
              + ((skg ^ (r1_ & 7)) << 3),                                      \
          ldsA[b_] + ((half) * 128 + 64 + w * 8) * 64);                        \
  } while (0)

#define STAGE_B(tile, half) do {                                               \
    const int b_ = (tile) & 1;                                                 \
    const int r0_ = sr0;                                                       \
    const int r1_ = 64 + sr0;                                                  \
    GLD16(Bm + (size_t)(n0 + (half) * 128 + r0_) * 2048 + (tile) * 64          \
              + ((skg ^ (r0_ & 7)) << 3),                                      \
          ldsB[b_] + ((half) * 128 + w * 8) * 64);                             \
    GLD16(Bm + (size_t)(n0 + (half) * 128 + r1_) * 2048 + (tile) * 64          \
              + ((skg ^ (r1_ & 7)) << 3),                                      \
          ldsB[b_] + ((half) * 128 + 64 + w * 8) * 64);                        \
  } while (0)

#define LDA_FRAG(dst, ab, q, mf, ks) do {                                      \
    const int row_ = wm * 128 + (q) * 32 + (mf) * 16 + fr;                     \
    const int kg_ = (ks) * 4 + fkg;                                            \
    dst = *(const bf16x8*)&ldsA[ab][row_ * 64 + ((kg_ ^ (row_ & 7)) << 3)];    \
  } while (0)
#define LDB_FRAG(dst, bb, nf, ks) do {                                         \
    const int row_ = wn * 64 + (nf) * 16 + fr;                                 \
    const int kg_ = (ks) * 4 + fkg;                                            \
    dst = *(const bf16x8*)&ldsB[bb][row_ * 64 + ((kg_ ^ (row_ & 7)) << 3)];    \
  } while (0)

  f32x4 acc[8][4] = {};

  // prologue: 14 loads; tile 0 resident after vmcnt(6)+barrier.
  STAGE_A(0, 0); STAGE_A(0, 1); STAGE_B(0, 0); STAGE_B(0, 1);
  STAGE_A(1, 0); STAGE_A(1, 1); STAGE_B(1, 0);
  asm volatile("s_waitcnt vmcnt(6)" ::: "memory");
  __builtin_amdgcn_s_barrier();

  for (int t = 0; t < NT; ++t) {
    const int abuf = t % 3;
    const int bbuf = t & 1;
    bf16x8 bfr[4][2];

    // ---- phase q0: all B frags + A quadrant 0; stage B(t+1,1)
    {
      bf16x8 af[2][2];
#pragma unroll
      for (int nf = 0; nf < 4; ++nf)
#pragma unroll
        for (int ks = 0; ks < 2; ++ks) LDB_FRAG(bfr[nf][ks], bbuf, nf, ks);
#pragma unroll
      for (int mf = 0; mf < 2; ++mf)
#pragma unroll
        for (int ks = 0; ks < 2; ++ks) LDA_FRAG(af[mf][ks], abuf, 0, mf, ks);
      if (t + 1 < NT) STAGE_B(t + 1, 1);
      __builtin_amdgcn_s_barrier();
      __builtin_amdgcn_s_setprio(1);
#pragma unroll
      for (int mf = 0; mf < 2; ++mf)
#pragma unroll
        for (int nf = 0; nf < 4; ++nf)
#pragma unroll
          for (int ks = 0; ks < 2; ++ks)
            acc[mf][nf] = __builtin_amdgcn_mfma_f32_16x16x32_bf16(
                af[mf][ks], bfr[nf][ks], acc[mf][nf], 0, 0, 0);
      __builtin_amdgcn_s_setprio(0);
    }

    // ---- phases q1..q3 (one barrier each)
#pragma unroll
    for (int q = 1; q < 4; ++q) {
      bf16x8 af[2][2];
#pragma unroll
      for (int mf = 0; mf < 2; ++mf)
#pragma unroll
        for (int ks = 0; ks < 2; ++ks) LDA_FRAG(af[mf][ks], abuf, q, mf, ks);
      if (q == 1) {
        if (t + 2 < NT) STAGE_A(t + 2, 0);
      } else if (q == 2) {
        if (t + 2 < NT) STAGE_A(t + 2, 1);
      } else {
        if (t + 2 < NT) STAGE_B(t + 2, 0);
        if (t == NT - 2)     asm volatile("s_waitcnt vmcnt(0)" ::: "memory");
        else if (t < NT - 2) asm volatile("s_waitcnt vmcnt(6)" ::: "memory");
      }
      __builtin_amdgcn_s_barrier();
      __builtin_amdgcn_s_setprio(1);
#pragma unroll
      for (int mf = 0; mf < 2; ++mf)
#pragma unroll
        for (int nf = 0; nf < 4; ++nf)
#pragma unroll
          for (int ks = 0; ks < 2; ++ks)
            acc[2 * q + mf][nf] = __builtin_amdgcn_mfma_f32_16x16x32_bf16(
                af[mf][ks], bfr[nf][ks], acc[2 * q + mf][nf], 0, 0, 0);
      __builtin_amdgcn_s_setprio(0);
    }
  }

  // epilogue through LDS: per-wave 128x72 padded tile, coalesced bf16x8 stores
  __syncthreads();
  const int proj = n0 >> 11;
  const int nb = n0 & 2047;
  __bf16* outp = proj == 0 ? o0 : proj == 1 ? o1 : proj == 2 ? o2 : o3;
  __bf16* ep = (__bf16*)smem + (size_t)w * 9216;
  const int crow = (l >> 4) * 4;
#pragma unroll
  for (int mf2 = 0; mf2 < 8; ++mf2)
#pragma unroll
    for (int nf = 0; nf < 4; ++nf)
#pragma unroll
      for (int r = 0; r < 4; ++r) {
        const int row = mf2 * 16 + crow + r;
        float vv = acc[mf2][nf][r];
        if (proj == 3) vv = 1.f / (1.f + expf(-vv));
        ep[row * 72 + nf * 16 + fr] = (__bf16)vv;
      }
#pragma unroll
  for (int it = 0; it < 16; ++it) {
    const int row = it * 8 + (l >> 3);
    const int c8 = (l & 7) * 8;
    const bf16x8 v8 = *(const bf16x8*)&ep[row * 72 + c8];
    *(bf16x8*)(outp + (size_t)(m0 + wm * 128 + row) * 2048 + nb + wn * 64 + c8) = v8;
  }
#undef STAGE_A
#undef STAGE_B
#undef LDA_FRAG
#undef LDB_FRAG
}

// ---------------------------------------------------------------------------
// Wo GEMM, pipelined: BM=128 x BN=256, 256 blocks (1/CU).
// ONE phase per K-tile: vmcnt -> barrier -> reads -> stages(t+2) -> 32 MFMA.
// ---------------------------------------------------------------------------
__global__ __launch_bounds__(512)
void gemm_wo(const __bf16* __restrict__ A, const __bf16* __restrict__ Bm,
             float* __restrict__ Cm)
{
  __shared__ __attribute__((aligned(16))) unsigned char smem[147456];
  __bf16 (*ldsA)[128 * 64] = (__bf16(*)[128 * 64])smem;              // 3 x 16KB
  __bf16 (*ldsB)[256 * 64] = (__bf16(*)[256 * 64])(smem + 49152);    // 3 x 32KB

  const int tid = threadIdx.x;
  const int w = tid >> 6, l = tid & 63;
  const int wm = w >> 2, wn = w & 3;
  const int m0 = blockIdx.y * 128, n0 = blockIdx.x * 256;
  const int NT = CC / 64;                     // 32 K-tiles

  const int sr0 = w * 8 + (l >> 3);
  const int skg = l & 7;
  const int fr = l & 15;
  const int fkg = l >> 4;

#define STAGE_AW(tile) do {                                                    \
    const int b_ = (tile) % 3;                                                 \
    const int r0_ = sr0;                                                       \
    const int r1_ = 64 + sr0;                                                  \
    GLD16(A + (size_t)(m0 + r0_) * 2048 + (tile) * 64                          \
              + ((skg ^ (r0_ & 7)) << 3),                                      \
          ldsA[b_] + (w * 8) * 64);                                            \
    GLD16(A + (size_t)(m0 + r1_) * 2048 + (tile) * 64                          \
              + ((skg ^ (r1_ & 7)) << 3),                                      \
          ldsA[b_] + (64 + w * 8) * 64);                                       \
  } while (0)

#define STAGE_BW(tile, half) do {                                              \
    const int b_ = (tile) % 3;                                                 \
    const int r0_ = sr0;                                                       \
    const int r1_ = 64 + sr0;                                                  \
    GLD16(Bm + (size_t)(n0 + (half) * 128 + r0_) * 2048 + (tile) * 64          \
              + ((skg ^ (r0_ & 7)) << 3),                                      \
          ldsB[b_] + ((half) * 128 + w * 8) * 64);                             \
    GLD16(Bm + (size_t)(n0 + (half) * 128 + r1_) * 2048 + (tile) * 64          \
              + ((skg ^ (r1_ & 7)) << 3),                                      \
          ldsB[b_] + ((half) * 128 + 64 + w * 8) * 64);                        \
  } while (0)

#define LDA_FRAGW(dst, ab, mf, ks) do {                                        \
    const int row_ = wm * 64 + (mf) * 16 + fr;                                 \
    const int kg_ = (ks) * 4 + fkg;                                            \
    dst = *(const bf16x8*)&ldsA[ab][row_ * 64 + ((kg_ ^ (row_ & 7)) << 3)];    \
  } while (0)
#define LDB_FRAGW(dst, bb, nf, ks) do {                                        \
    const int row_ = wn * 64 + (nf) * 16 + fr;                                 \
    const int kg_ = (ks) * 4 + fkg;                                            \
    dst = *(const bf16x8*)&ldsB[bb][row_ * 64 + ((kg_ ^ (row_ & 7)) << 3)];    \
  } while (0)

  f32x4 acc[4][4] = {};

  // prologue: tiles 0 and 1 staged (12 loads).
  STAGE_BW(0, 0); STAGE_BW(0, 1); STAGE_AW(0);
  STAGE_BW(1, 0); STAGE_BW(1, 1); STAGE_AW(1);

  for (int t = 0; t < NT; ++t) {
    const int buf = t % 3;
    bf16x8 bfr[4][2];
    bf16x8 af[4][2];

    if (t == NT - 1) asm volatile("s_waitcnt vmcnt(0)" ::: "memory");
    else             asm volatile("s_waitcnt vmcnt(6)" ::: "memory");
    __builtin_amdgcn_s_barrier();

#pragma unroll
    for (int nf = 0; nf < 4; ++nf)
#pragma unroll
      for (int ks = 0; ks < 2; ++ks) LDB_FRAGW(bfr[nf][ks], buf, nf, ks);
#pragma unroll
    for (int mf = 0; mf < 4; ++mf)
#pragma unroll
      for (int ks = 0; ks < 2; ++ks) LDA_FRAGW(af[mf][ks], buf, mf, ks);

    if (t + 2 < NT) { STAGE_BW(t + 2, 0); STAGE_BW(t + 2, 1); STAGE_AW(t + 2); }

    __builtin_amdgcn_s_setprio(1);
#pragma unroll
    for (int mf = 0; mf < 4; ++mf)
#pragma unroll
      for (int nf = 0; nf < 4; ++nf)
#pragma unroll
        for (int ks = 0; ks < 2; ++ks)
          acc[mf][nf] = __builtin_amdgcn_mfma_f32_16x16x32_bf16(
              af[mf][ks], bfr[nf][ks], acc[mf][nf], 0, 0, 0);
    __builtin_amdgcn_s_setprio(0);
  }

  // epilogue: per-wave 64x68 f32 tile in LDS -> float4 stores
  __syncthreads();
  float* ep = (float*)smem + (size_t)w * (64 * 68);
  const int crow = (l >> 4) * 4;
#pragma unroll
  for (int mf = 0; mf < 4; ++mf)
#pragma unroll
    for (int nf = 0; nf < 4; ++nf)
#pragma unroll
      for (int r = 0; r < 4; ++r)
        ep[(mf * 16 + crow + r) * 68 + nf * 16 + fr] = acc[mf][nf][r];
#pragma unroll
  for (int it = 0; it < 16; ++it) {
    const int row = it * 4 + (l >> 4);
    const int c4 = (l & 15) * 4;
    const float4 v4 = *(const float4*)&ep[row * 68 + c4];
    *(float4*)(Cm + (size_t)(m0 + wm * 64 + row) * 2048 + n0 + wn * 64 + c4) = v4;
  }
#undef STAGE_AW
#undef STAGE_BW
#undef LDA_FRAGW
#undef LDB_FRAGW
}

// ---------------------------------------------------------------------------
// fused causal dwconv(K=4)+silu + (k,v) transpose.
// ---------------------------------------------------------------------------
__global__ __launch_bounds__(256)
void conv_tr(const __bf16* __restrict__ u_q, const __bf16* __restrict__ u_k,
             const __bf16* __restrict__ u_v, const float* __restrict__ wq,
             const float* __restrict__ wk, const float* __restrict__ wv,
             __bf16* __restrict__ qbf, __bf16* __restrict__ kbf,
             __bf16* __restrict__ kT, __bf16* __restrict__ vT, float qscale)
{
  const int t0 = blockIdx.x * 64, c0 = blockIdx.y * 64;
  const int which = blockIdx.z / BB, b = blockIdx.z % BB;
  const __bf16* u = which == 0 ? u_q : which == 1 ? u_k : u_v;
  const float* wc = which == 0 ? wq : which == 1 ? wk : wv;
  const float scale = which == 0 ? qscale : 1.f;
  const int tid = threadIdx.x;
  __shared__ __attribute__((aligned(16))) __bf16 tile[64][72];

#pragma unroll
  for (int it = 0; it < 2; ++it) {
    const int idx = tid + it * 256;
    const int tl = idx >> 3, g = idx & 7;
    const int t = t0 + tl;
    const int c8 = c0 + g * 8;
    const size_t base = ((size_t)(b * TT + t)) * CC + c8;
    const bf16x8 z = {};
    const bf16x8 uu0 = *(const bf16x8*)(u + base);
    const bf16x8 uu1 = (t >= 1) ? *(const bf16x8*)(u + base - CC)     : z;
    const bf16x8 uu2 = (t >= 2) ? *(const bf16x8*)(u + base - 2 * CC) : z;
    const bf16x8 uu3 = (t >= 3) ? *(const bf16x8*)(u + base - 3 * CC) : z;
    bf16x8 o;
#pragma unroll
    for (int jj = 0; jj < 8; ++jj) {
      const float4 wv4 = *(const float4*)(wc + (size_t)(c8 + jj) * 4);
      const float vv = wv4.x * (float)uu3[jj] + wv4.y * (float)uu2[jj]
                     + wv4.z * (float)uu1[jj] + wv4.w * (float)uu0[jj];
      o[jj] = (__bf16)(vv / (1.f + expf(-vv)) * scale);
    }
    if (which == 0) *(bf16x8*)(qbf + base) = o;
    if (which == 1) *(bf16x8*)(kbf + base) = o;
    if (which >= 1) *(bf16x8*)&tile[tl][g * 8] = o;
  }
  if (which >= 1) {
    __syncthreads();
    const int h = c0 >> 7, d0 = c0 & 127;
    const int bh = b * HH + h;
    __bf16* dst = (which == 1) ? kT : vT;
#pragma unroll
    for (int it = 0; it < 2; ++it) {
      const int idx = tid + it * 256;
      const int dl = idx >> 3, g = idx & 7;
      bf16x8 o;
#pragma unroll
      for (int jj = 0; jj < 8; ++jj) o[jj] = tile[g * 8 + jj][dl];
      *(bf16x8*)(dst + ((size_t)(bh * DD + d0 + dl)) * TT + t0 + g * 8) = o;
    }
  }
}

// ---------------------------------------------------------------------------
// Phase A (MFMA): contribT[e][d] = sum_s (w_s k_s[d]) v_s[e] -> bf16 out.
// ---------------------------------------------------------------------------
__global__ __launch_bounds__(256)
void phaseA_mfma(const __bf16* __restrict__ kT, const __bf16* __restrict__ vT,
                 const float* __restrict__ beta, __bf16* __restrict__ contribT,
                 float* __restrict__ decay)
{
  const int c = blockIdx.x, h = blockIdx.y, b = blockIdx.z;
  const int bh = b * HH + h;
  const int tid = threadIdx.x;
  const int w = tid >> 6, lane = tid & 63;
  const int wm = w >> 1, wn = w & 1;

  __shared__ __attribute__((aligned(16))) __bf16 bufVT[128 * 128];
  __shared__ __attribute__((aligned(16))) __bf16 bufKW[128 * 128];
  __shared__ float lc[CHUNK], bsh[CHUNK], wgt[CHUNK];

  {
    const __bf16* vbase = vT + ((size_t)bh * DD) * TT + c * CHUNK;
#pragma unroll
    for (int jj = 0; jj < 8; ++jj) {
      const int row = w * 32 + jj * 4 + (lane >> 4);
      const int g = lane & 15;
      GLD16(vbase + (size_t)row * TT + ((g ^ (row & 7)) << 3),
            bufVT + (w * 32 + jj * 4) * 128);
    }
  }

  if (tid < CHUNK) {
    const float bv = beta[(size_t)(b * TT + c * CHUNK + tid) * HH + h];
    bsh[tid] = bv;
    lc[tid] = log1pf(-bv);
  }
  __syncthreads();
  for (int off = 1; off < CHUNK; off <<= 1) {
    float add = 0.f;
    if (tid < CHUNK && tid >= off) add = lc[tid - off];
    __syncthreads();
    if (tid < CHUNK) lc[tid] += add;
    __syncthreads();
  }
  const float lend = lc[CHUNK - 1];
  if (tid < CHUNK) wgt[tid] = bsh[tid] * expf(lend - lc[tid]);
  if (tid == 0) decay[(size_t)bh * NC + c] = expf(lend);
  __syncthreads();

  {
    const __bf16* kbase = kT + ((size_t)bh * DD) * TT + c * CHUNK;
#pragma unroll
    for (int it = 0; it < 8; ++it) {
      const int idx = tid + it * 256;
      const int d = idx >> 4, g = idx & 15;
      const bf16x8 kv = *(const bf16x8*)(kbase + (size_t)d * TT + g * 8);
      bf16x8 o;
#pragma unroll
      for (int jj = 0; jj < 8; ++jj)
        o[jj] = (__bf16)((float)kv[jj] * wgt[g * 8 + jj]);
      *(bf16x8*)(bufKW + d * 128 + ((g ^ (d & 7)) << 3)) = o;
    }
  }
  asm volatile("s_waitcnt vmcnt(0)" ::: "memory");
  __syncthreads();

  f32x4 acc[4][4] = {};
#pragma unroll
  for (int ks = 0; ks < 4; ++ks) {
    bf16x8 a[4], bq[4];
    const int kg = ks * 4 + (lane >> 4);
#pragma unroll
    for (int f = 0; f < 4; ++f) a[f]  = ldfrag(bufVT, wm * 64 + f * 16 + (lane & 15), kg);
#pragma unroll
    for (int f = 0; f < 4; ++f) bq[f] = ldfrag(bufKW, wn * 64 + f * 16 + (lane & 15), kg);
#pragma unroll
    for (int i = 0; i < 4; ++i)
#pragma unroll
      for (int j = 0; j < 4; ++j)
        acc[i][j] = __builtin_amdgcn_mfma_f32_16x16x32_bf16(a[i], bq[j], acc[i][j], 0, 0, 0);
  }

  __bf16* cp = contribT + ((size_t)(bh * NC + c) << 14);
  const int crow = (lane >> 4) * 4;
#pragma unroll
  for (int i = 0; i < 4; ++i)
#pragma unroll
    for (int j = 0; j < 4; ++j) {
      const int dd = wn * 64 + j * 16 + (lane & 15);
#pragma unroll
      for (int r = 0; r < 4; ++r) {
        const int e = wm * 64 + i * 16 + crow + r;
        cp[(size_t)e * 128 + dd] = (__bf16)acc[i][j][r];
      }
    }
}

// ---------------------------------------------------------------------------
// Phase B: absorbs both state transposes. contrib bf16 in, states bf16 out.
// ---------------------------------------------------------------------------
__global__ __launch_bounds__(256)
void phaseB_T(const float* __restrict__ st0, const __bf16* __restrict__ contribT,
              const float* __restrict__ decay, __bf16* __restrict__ statesT,
              float* __restrict__ stOut)
{
  const size_t gid = (size_t)blockIdx.x * 256 + threadIdx.x;
  const int bh = (int)(gid >> 14);
  const int ed = (int)(gid & 16383);
  const int e = ed >> 7, d = ed & 127;
  const size_t tidx = ((size_t)bh << 14) + (size_t)d * 128 + e;
  float s = st0[tidx];
  const float* dc = decay + (size_t)bh * NC;
#pragma unroll
  for (int c = 0; c < NC; ++c) {
    const size_t off = ((size_t)(bh * NC + c) << 14) + ed;
    statesT[off] = (__bf16)s;
    s = fmaf(dc[c], s, (float)contribT[off]);
  }
  stOut[tidx] = s;
}

// ---------------------------------------------------------------------------
// Phase C v2 (MFMA) + fused GroupNorm partial stats. att stored as bf16
// (stats computed exactly in f32 from registers).
// ---------------------------------------------------------------------------
__global__ __launch_bounds__(256)
void phaseC_mfma(const __bf16* __restrict__ qb, const __bf16* __restrict__ kb,
                 const __bf16* __restrict__ vT, const float* __restrict__ beta,
                 const __bf16* __restrict__ statesT, __bf16* __restrict__ att,
                 float* __restrict__ partials)
{
  const int c = blockIdx.x, h = blockIdx.y, b = blockIdx.z;
  const int bh = b * HH + h;
  const int tid = threadIdx.x;
  const int w = tid >> 6, lane = tid & 63;
  const int wm = w >> 1, wn = w & 1;

  __shared__ __attribute__((aligned(16))) __bf16 bufA[128 * 128];  // K -> P
  __shared__ __attribute__((aligned(16))) __bf16 bufB[128 * 128];  // S0T -> V
  __shared__ float lc[CHUNK], bsh[CHUNK];
  __shared__ float s1[256], s2[256];

  // direct Q fragment loads into registers
  bf16x8 qf[4][4];
  {
    const __bf16* qbase = qb + ((size_t)(b * TT + c * CHUNK + wm * 64 + (lane & 15))) * CC
                        + h * DD + (lane >> 4) * 8;
#pragma unroll
    for (int f = 0; f < 4; ++f)
#pragma unroll
      for (int ks = 0; ks < 4; ++ks)
        qf[f][ks] = *(const bf16x8*)(qbase + (size_t)f * 16 * CC + ks * 32);
  }

  // stage K -> bufA, S0T -> bufB (async; hidden under beta scan)
  {
    const __bf16* kbase = kb + ((size_t)(b * TT + c * CHUNK)) * CC + h * DD;
    const __bf16* sbase = statesT + ((size_t)(bh * NC + c) << 14);
#pragma unroll
    for (int jj = 0; jj < 8; ++jj) {
      const int row = w * 32 + jj * 4 + (lane >> 4);
      const int g = lane & 15;
      GLD16(kbase + (size_t)row * CC + ((g ^ (row & 7)) << 3),
            bufA + (w * 32 + jj * 4) * 128);
      GLD16(sbase + (size_t)row * 128 + ((g ^ (row & 7)) << 3),
            bufB + (w * 32 + jj * 4) * 128);
    }
  }

  if (tid < CHUNK) {
    const float bv = beta[(size_t)(b * TT + c * CHUNK + tid) * HH + h];
    bsh[tid] = bv;
    lc[tid] = log1pf(-bv);
  }
  __syncthreads();
  for (int off = 1; off < CHUNK; off <<= 1) {
    float add = 0.f;
    if (tid < CHUNK && tid >= off) add = lc[tid - off];
    __syncthreads();
    if (tid < CHUNK) lc[tid] += add;
    __syncthreads();
  }

  asm volatile("s_waitcnt vmcnt(0)" ::: "memory");
  __syncthreads();

  // S = Q K^T
  f32x4 accS[4][4] = {};
#pragma unroll
  for (int ks = 0; ks < 4; ++ks) {
    bf16x8 bq[4];
    const int kg = ks * 4 + (lane >> 4);
#pragma unroll
    for (int f = 0; f < 4; ++f) bq[f] = ldfrag(bufA, wn * 64 + f * 16 + (lane & 15), kg);
#pragma unroll
    for (int i = 0; i < 4; ++i)
#pragma unroll
      for (int j = 0; j < 4; ++j)
        accS[i][j] = __builtin_amdgcn_mfma_f32_16x16x32_bf16(qf[i][ks], bq[j], accS[i][j], 0, 0, 0);
  }

  // accO = Q S0T
  f32x4 accO[4][4] = {};
#pragma unroll
  for (int ks = 0; ks < 4; ++ks) {
    bf16x8 bq[4];
    const int kg = ks * 4 + (lane >> 4);
#pragma unroll
    for (int f = 0; f < 4; ++f) bq[f] = ldfrag(bufB, wn * 64 + f * 16 + (lane & 15), kg);
#pragma unroll
    for (int i = 0; i < 4; ++i)
#pragma unroll
      for (int j = 0; j < 4; ++j)
        accO[i][j] = __builtin_amdgcn_mfma_f32_16x16x32_bf16(qf[i][ks], bq[j], accO[i][j], 0, 0, 0);
  }
  const int crow = (lane >> 4) * 4;
#pragma unroll
  for (int i = 0; i < 4; ++i)
#pragma unroll
    for (int r = 0; r < 4; ++r) {
      const float el = expf(lc[wm * 64 + i * 16 + crow + r]);
#pragma unroll
      for (int j = 0; j < 4; ++j) accO[i][j][r] *= el;
    }

  __syncthreads();

  // stage V -> bufB (hidden under P transform)
  {
    const __bf16* vbase = vT + ((size_t)bh * DD) * TT + c * CHUNK;
#pragma unroll
    for (int jj = 0; jj < 8; ++jj) {
      const int row = w * 32 + jj * 4 + (lane >> 4);
      const int g = lane & 15;
      GLD16(vbase + (size_t)row * TT + ((g ^ (row & 7)) << 3),
            bufB + (w * 32 + jj * 4) * 128);
    }
  }
  // transform S -> P, write bf16 swizzled into bufA
  {
    float lcs[4], bss[4];
#pragma unroll
    for (int j = 0; j < 4; ++j) {
      const int s = wn * 64 + j * 16 + (lane & 15);
      lcs[j] = lc[s]; bss[j] = bsh[s];
    }
#pragma unroll
    for (int i = 0; i < 4; ++i)
#pragma unroll
      for (int r = 0; r < 4; ++r) {
        const int t = wm * 64 + i * 16 + crow + r;
        const float lct = lc[t];
#pragma unroll
        for (int j = 0; j < 4; ++j) {
          const int s = wn * 64 + j * 16 + (lane & 15);
          float p = 0.f;
          if (s <= t) p = accS[i][j][r] * bss[j] * expf(lct - lcs[j]);
          bufA[t * 128 + (((s >> 3) ^ (t & 7)) << 3) + (s & 7)] = (__bf16)p;
        }
      }
  }
  asm volatile("s_waitcnt vmcnt(0)" ::: "memory");
  __syncthreads();

  // accO += P V^T
#pragma unroll
  for (int ks = 0; ks < 4; ++ks) {
    bf16x8 a[4], bq[4];
    const int kg = ks * 4 + (lane >> 4);
#pragma unroll
    for (int f = 0; f < 4; ++f) a[f]  = ldfrag(bufA, wm * 64 + f * 16 + (lane & 15), kg);
#pragma unroll
    for (int f = 0; f < 4; ++f) bq[f] = ldfrag(bufB, wn * 64 + f * 16 + (lane & 15), kg);
#pragma unroll
    for (int i = 0; i < 4; ++i)
#pragma unroll
      for (int j = 0; j < 4; ++j)
        accO[i][j] = __builtin_amdgcn_mfma_f32_16x16x32_bf16(a[i], bq[j], accO[i][j], 0, 0, 0);
  }

  // epilogue: store att (bf16) + accumulate exact GN partial stats (f32)
  float lsum = 0.f, lsq = 0.f;
  __bf16* obase = att + ((size_t)(b * TT + c * CHUNK)) * CC + h * DD;
#pragma unroll
  for (int i = 0; i < 4; ++i)
#pragma unroll
    for (int j = 0; j < 4; ++j) {
      const int e = wn * 64 + j * 16 + (lane & 15);
#pragma unroll
      for (int r = 0; r < 4; ++r) {
        const int t = wm * 64 + i * 16 + crow + r;
        const float vv = accO[i][j][r];
        obase[(size_t)t * CC + e] = (__bf16)vv;
        lsum += vv;
        lsq  += vv * vv;
      }
    }
  s1[tid] = lsum; s2[tid] = lsq;
  __syncthreads();
  for (int off = 128; off; off >>= 1) {
    if (tid < off) { s1[tid] += s1[tid + off]; s2[tid] += s2[tid + off]; }
    __syncthreads();
  }
  if (tid == 0) {
    partials[(size_t)(bh * NC + c) * 2]     = s1[0];
    partials[(size_t)(bh * NC + c) * 2 + 1] = s2[0];
  }
}

// ---------------------------------------------------------------------------
// normalize + gate -> bf16; absorbs GN partial combine. att is bf16 now.
// ---------------------------------------------------------------------------
__global__ __launch_bounds__(256)
void norm_gate(const __bf16* __restrict__ att, const __bf16* __restrict__ gate,
               const float* __restrict__ partials, __bf16* __restrict__ g)
{
  __shared__ float sm[8], sr[8];
  const int tid = threadIdx.x;
  const size_t gid0 = (size_t)blockIdx.x * 1024;
  const int b = (int)(gid0 >> 22);
  const int h0 = ((int)(gid0 & 2047)) >> 7;     // 0 or 8
  if (tid < 8) {
    const int bh = b * HH + h0 + tid;
    float s = 0.f, q = 0.f;
#pragma unroll
    for (int cc = 0; cc < NC; ++cc) {
      s += partials[(size_t)(bh * NC + cc) * 2];
      q += partials[(size_t)(bh * NC + cc) * 2 + 1];
    }
    const float n = (float)(TT * DD);
    const float mean = s / n;
    sm[tid] = mean;
    sr[tid] = rsqrtf(q / n - mean * mean + GN_EPS);
  }
  __syncthreads();
  const size_t gid = gid0 + (size_t)tid * 4;
  const int hl = (tid * 4) >> 7;                // 0..7
  const float mean = sm[hl], rstd = sr[hl];
  const bf16x4 a = *(const bf16x4*)(att + gid);
  const bf16x4 gt = *(const bf16x4*)(gate + gid);
  bf16x4 o;
  o[0] = (__bf16)(((float)a[0] - mean) * rstd * (float)gt[0]);
  o[1] = (__bf16)(((float)a[1] - mean) * rstd * (float)gt[1]);
  o[2] = (__bf16)(((float)a[2] - mean) * rstd * (float)gt[2]);
  o[3] = (__bf16)(((float)a[3] - mean) * rstd * (float)gt[3]);
  *(bf16x4*)(g + gid) = o;
}

// ---------------------------------------------------------------------------
extern "C" void kernel_launch(void* const* d_in, const int* in_sizes, int n_in,
                              void* d_out, int out_size, void* d_ws, size_t ws_size,
                              hipStream_t stream)
{
  const float* x      = (const float*)d_in[0];
  const float* st0    = (const float*)d_in[1];
  const float* Wq     = (const float*)d_in[2];
  const float* Wk     = (const float*)d_in[3];
  const float* Wv     = (const float*)d_in[4];
  const float* Wbeta  = (const float*)d_in[5];
  const float* Wgate  = (const float*)d_in[6];
  const float* Wo     = (const float*)d_in[7];
  const float* wqc    = (const float*)d_in[8];
  const float* wkc    = (const float*)d_in[9];
  const float* wvc    = (const float*)d_in[10];

  float* ws = (float*)d_ws;
  __bf16* qbf  = (__bf16*)(ws + 0);           // 8.4M bf16
  __bf16* kbf  = (__bf16*)(ws + 4194304);     // 8.4M bf16
  __bf16* u_v  = (__bf16*)(ws + 8388608);     // pre-act v; -> statesT after conv
  __bf16* statesT = (__bf16*)(ws + 8388608);  // (phaseB; u_v dead by then)
  __bf16* kT   = (__bf16*)(ws + 12582912);    // -> gbf after phaseC
  __bf16* gbf  = (__bf16*)(ws + 12582912);
  __bf16* vT   = (__bf16*)(ws + 16777216);
  __bf16* xbf  = (__bf16*)(ws + 20971520);    // dead after gemm_big
  __bf16* contribT = (__bf16*)(ws + 20971520);// 8.4M bf16, overlays xbf
  __bf16* Wcat = (__bf16*)(ws + 25165824);    // 16.8M bf16, dead after gemm_big
  __bf16* gatebuf = (__bf16*)(ws + 33554432); // 8.4M bf16, alive GEMM -> norm_gate
  float* betab    = ws + 37748736;            // 65536
  float* decay    = ws + 37814272;            // 512
  float* partials = ws + 37814848;            // 1024
  __bf16* Wob  = (__bf16*)(ws + 38864448);    // 4.2M bf16

  float* y_out  = (float*)d_out;
  float* st_out = (float*)d_out + (size_t)BB * TT * EE;
  __bf16* u_q = (__bf16*)d_out;               // bf16 [0, 8388608)
  __bf16* u_k = (__bf16*)d_out + 8388608;     // bf16 [8388608, 16777216)
  __bf16* att = (__bf16*)d_out;               // bf16 [0, 8388608) after conv

  const dim3 blk(256);
  const dim3 gBig(8192 / 256, (BB * TT) / 256);    // 32 x 16 = 512 blocks
  const dim3 gWo(EE / 256, (BB * TT) / 128);       // 8 x 32 = 256 blocks
  const dim3 gConv(TT / 64, CC / 64, 3 * BB);      // 32 x 32 x 6
  const dim3 gScan(NC, HH, BB);
  const float qscale = 0.08838834764831845f;

  // weight conversions
  convert_w<<<dim3(20480), blk, 0, stream>>>(Wq, Wk, Wv, Wgate, Wo, Wcat, Wob);

  // beta (fp32) + xbf emission
  beta_ker<<<dim3((BB * TT) / 4), blk, 0, stream>>>(x, Wbeta, betab, xbf);

  // merged QKV+gate projection (round-8 schedule)
  gemm_big<<<gBig, dim3(512), 0, stream>>>(xbf, Wcat, u_q, u_k, u_v, gatebuf);

  // conv/silu + k,v transposes, fused
  conv_tr<<<gConv, blk, 0, stream>>>(u_q, u_k, u_v, wqc, wkc, wvc,
                                     qbf, kbf, kT, vT, qscale);

  // chunked delta scan (MFMA); phaseB absorbs the state transposes
  phaseA_mfma<<<gScan, blk, 0, stream>>>(kT, vT, betab, contribT, decay);
  phaseB_T<<<dim3((BB * HH * DD * DD) / 256), blk, 0, stream>>>(st0, contribT, decay, statesT, st_out);
  phaseC_mfma<<<gScan, blk, 0, stream>>>(qbf, kbf, vT, betab, statesT, att, partials);

  // groupnorm (combine fused) + gate -> bf16
  norm_gate<<<dim3((BB * TT * CC) / 1024), blk, 0, stream>>>(att, gatebuf, partials, gbf);

  // y = g @ Wo^T (1-phase pipelined 128x256 structure)
  gemm_wo<<<gWo, dim3(512), 0, stream>>>(gbf, Wob, y_out);
}